// Round 5
// baseline (2011.354 us; speedup 1.0000x reference)
//
#include <hip/hip_runtime.h>
#include <hip/hip_bf16.h>
#include <stdint.h>

#define C_IN  128
#define O_CH  256
#define NH    5
#define TSIZE 2048
#define HWDIM 56
#define NPIX  3136        // 56*56
#define KTOT  1152        // 128*9
#define ADIM  1161        // KTOT + 9
#define NHC   8           // global-hist copies (atomic spread across XCDs)
#define LBINS 192         // LDS hist bins per hash (|bucket| < 192 in practice; spill path covers rest)

// ---------------- table build (fp64 decision path — verified R3/R4) ----------------
__global__ void k_norms(const float* __restrict__ w, double* __restrict__ ssbuf) {
  int o = blockIdx.x, t = threadIdx.x;            // 64 threads
  double ss = 0.;
  for (int i = t; i < KTOT; i += 64) { double v = (double)w[o * KTOT + i]; ss += v * v; }
  #pragma unroll
  for (int off = 32; off > 0; off >>= 1) ss += __shfl_down(ss, off, 64);
  if (t == 0) ssbuf[o] = ss;
}

__global__ __launch_bounds__(256) void k_table(const float* __restrict__ w,
    const float* __restrict__ a, const float* __restrict__ b_unit,
    const double* __restrict__ ssbuf, int* __restrict__ kbucket) {
  int o = blockIdx.x, t = threadIdx.x;
  __shared__ double red[256];
  __shared__ double r6[6][256];
  red[t] = ssbuf[t];
  __syncthreads();
  for (int s = 128; s; s >>= 1) { if (t < s) red[t] = fmax(red[t], red[t + s]); __syncthreads(); }
  double scale = 0.99 / sqrt(red[0]);             // U / denom
  double pd0 = 0, pd1 = 0, pd2 = 0, pd3 = 0, pd4 = 0, ss2 = 0;
  for (int i = t; i < KTOT; i += 256) {
    double wv = scale * (double)w[o * KTOT + i];
    ss2 += wv * wv;
    pd0 += wv * (double)a[0 * ADIM + i];
    pd1 += wv * (double)a[1 * ADIM + i];
    pd2 += wv * (double)a[2 * ADIM + i];
    pd3 += wv * (double)a[3 * ADIM + i];
    pd4 += wv * (double)a[4 * ADIM + i];
  }
  r6[0][t] = ss2; r6[1][t] = pd0; r6[2][t] = pd1; r6[3][t] = pd2; r6[4][t] = pd3; r6[5][t] = pd4;
  __syncthreads();
  for (int s = 128; s; s >>= 1) {
    if (t < s) { for (int q = 0; q < 6; ++q) r6[q][t] += r6[q][t + s]; }
    __syncthreads();
  }
  if (t == 0) {
    double nrm = sqrt(r6[0][0]);
    double q = nrm;
    double dp[NH] = {0, 0, 0, 0, 0};
    for (int j = 0; j < 9; ++j) {
      q = q * q;                                   // nrm^2, nrm^4, ..., nrm^512
      #pragma unroll
      for (int h = 0; h < NH; ++h) dp[h] += q * (double)a[h * ADIM + KTOT + j];
    }
    #pragma unroll
    for (int h = 0; h < NH; ++h) {
      double tot = r6[1 + h][0] + dp[h] + (double)b_unit[h] * 4.0;
      int hv = (int)floor(tot * 0.25);
      int bk = hv % TSIZE; if (bk < 0) bk = -bk;
      kbucket[o * NH + h] = bk;
    }
  }
}

// ---------------- vote conv: fp32, channel-split, small LDS hist ----------------
// block = 64 pixels x 4 channel-groups (32 ch each); grid 1568 (= 100352/64)
__global__ __launch_bounds__(256) void k_vote2(const float* __restrict__ x,
    const float* __restrict__ a, const float* __restrict__ b_unit, int* __restrict__ ghist) {
  __shared__ float red[4][NH][64];                // [g][h][px] — conflict-free
  __shared__ int   lh[NH * LBINS];
  int t = threadIdx.x;
  int px = t & 63, g = t >> 6;                    // wave = one channel-group, lanes = pixels
  for (int i = t; i < NH * LBINS; i += 256) lh[i] = 0;
  int p = blockIdx.x * 64 + px;                   // 1568*64 = 100352 exact
  int bb = p / NPIX; int rem = p - bb * NPIX;
  int y = rem / HWDIM; int xx = rem - y * HWDIM;
  bool x0 = xx > 0, x2 = xx < HWDIM - 1, y0 = y > 0, y2 = y < HWDIM - 1;
  const float* xb = x + ((size_t)bb * C_IN + g * 32) * NPIX + y * HWDIM + xx;
  float acc[NH] = {0, 0, 0, 0, 0};
  for (int c = 0; c < 32; ++c) {
    const float* xc = xb + c * NPIX;
    float v0 = 0, v1 = 0, v2 = 0, v3 = 0, v5 = 0, v6 = 0, v7 = 0, v8 = 0;
    float v4 = xc[0];
    if (x0) v3 = xc[-1];
    if (x2) v5 = xc[1];
    if (y0) { v1 = xc[-HWDIM]; if (x0) v0 = xc[-HWDIM - 1]; if (x2) v2 = xc[-HWDIM + 1]; }
    if (y2) { v7 = xc[HWDIM];  if (x0) v6 = xc[HWDIM - 1];  if (x2) v8 = xc[HWDIM + 1]; }
    #pragma unroll
    for (int h = 0; h < NH; ++h) {
      const float* ah = a + h * ADIM + (g * 32 + c) * 9;   // uniform -> scalar loads
      acc[h] += v0 * ah[0] + v1 * ah[1] + v2 * ah[2] + v3 * ah[3] + v4 * ah[4]
              + v5 * ah[5] + v6 * ah[6] + v7 * ah[7] + v8 * ah[8];
    }
  }
  #pragma unroll
  for (int h = 0; h < NH; ++h) red[g][h][px] = acc[h];
  __syncthreads();
  int* gh = ghist + (blockIdx.x & (NHC - 1)) * NH * TSIZE;
  if (g == 0) {                                   // threads 0..63 finalize their pixel
    #pragma unroll
    for (int h = 0; h < NH; ++h) {
      float s = red[0][h][px] + red[1][h][px] + red[2][h][px] + red[3][h][px];
      const float* ah = a + h * ADIM + KTOT;      // appended 0.5 channel (zero pad ring)
      float e = ah[4];
      if (x0) e += ah[3];
      if (x2) e += ah[5];
      if (y0) { e += ah[1]; if (x0) e += ah[0]; if (x2) e += ah[2]; }
      if (y2) { e += ah[7]; if (x0) e += ah[6]; if (x2) e += ah[8]; }
      s += 0.5f * e;
      int hv = (int)floorf((s + b_unit[h] * 4.0f) * 0.25f);
      int bk = hv % TSIZE; if (bk < 0) bk = -bk;
      if (bk < LBINS) atomicAdd(&lh[h * LBINS + bk], 1);
      else            atomicAdd(&gh[h * TSIZE + bk], 1);     // rare spill
    }
  }
  __syncthreads();
  for (int i = t; i < NH * LBINS; i += 256) {
    int v = lh[i];
    if (v) { int h = i / LBINS, bk = i - h * LBINS; atomicAdd(&gh[h * TSIZE + bk], v); }
  }
}

// ---------------- select + active mask + compaction ----------------
__global__ __launch_bounds__(256) void k_select(const int* __restrict__ ghist,
    const int* __restrict__ kbucket, float* __restrict__ mscale,
    int* __restrict__ actlist, int* __restrict__ nact) {
  int t = threadIdx.x;
  __shared__ int rc[256], ri[256], sel[NH], scn[256];
  for (int h = 0; h < NH; ++h) {
    int bc = -1, bi = 0;
    for (int i = t; i < TSIZE; i += 256) {        // ascending i + strict '>' = first-max
      int c = 0;
      #pragma unroll
      for (int k = 0; k < NHC; ++k) c += ghist[(k * NH + h) * TSIZE + i];
      if (c > bc) { bc = c; bi = i; }
    }
    rc[t] = bc; ri[t] = bi;
    __syncthreads();
    for (int s = 128; s; s >>= 1) {
      if (t < s) {
        if (rc[t + s] > rc[t] || (rc[t + s] == rc[t] && ri[t + s] < ri[t])) {
          rc[t] = rc[t + s]; ri[t] = ri[t + s];
        }
      }
      __syncthreads();
    }
    if (t == 0) sel[h] = ri[0];
    __syncthreads();
  }
  bool act = false;
  #pragma unroll
  for (int i = 0; i < NH; ++i) {
    int kb = kbucket[t * NH + i];
    #pragma unroll
    for (int j = 0; j < NH; ++j) act = act || (kb == sel[j]);
  }
  scn[t] = act ? 1 : 0;
  __syncthreads();
  // Hillis-Steele inclusive scan
  for (int off = 1; off < 256; off <<= 1) {
    int v = scn[t];
    if (t >= off) v += scn[t - off];
    __syncthreads();
    scn[t] = v;
    __syncthreads();
  }
  int n = scn[255];
  if (n == 0) {                                   // fallback: all active
    actlist[t] = t;
    mscale[t] = 1.0f;
    if (t == 0) *nact = 256;
  } else {
    if (act) actlist[scn[t] - 1] = t;
    mscale[t] = act ? 256.0f / (float)n : 0.0f;
    if (t == 0) *nact = n;
  }
}

// ---------------- active-only fp32 direct conv ----------------
// grid (b*14+yq, channel-octet, c-quarter); blocks past nact exit immediately.
// out must be pre-zeroed; partial c-quarter sums combine via float atomicAdd.
__global__ __launch_bounds__(256) void k_aconv(const float* __restrict__ x,
    const float* __restrict__ w, const float* __restrict__ bias,
    const float* __restrict__ mscale, const int* __restrict__ actlist,
    const int* __restrict__ nact_p, float* __restrict__ out) {
  int na = *nact_p;
  int og = blockIdx.y;
  if (og * 8 >= na) return;
  int nloc = min(8, na - og * 8);
  int cq = blockIdx.z;                            // 32-channel quarter
  int yq = blockIdx.x % 14, b = blockIdx.x / 14;
  __shared__ float wsm[8][288];                   // 9.2 KB
  __shared__ int ol[8];
  int t = threadIdx.x;
  if (t < 8) ol[t] = (t < nloc) ? actlist[og * 8 + t] : 0;
  __syncthreads();
  for (int i = t; i < nloc * 288; i += 256) {
    int j = i / 288, r = i - j * 288;
    wsm[j][r] = w[(size_t)ol[j] * KTOT + cq * 288 + r];
  }
  __syncthreads();
  if (t >= 224) return;                           // 4 rows x 56 cols
  int y = yq * 4 + t / HWDIM, xx = t % HWDIM;
  bool x0 = xx > 0, x2 = xx < HWDIM - 1, y0 = y > 0, y2 = y < HWDIM - 1;
  const float* xb = x + ((size_t)b * C_IN + cq * 32) * NPIX + y * HWDIM + xx;
  float acc[8] = {0, 0, 0, 0, 0, 0, 0, 0};
  for (int c = 0; c < 32; ++c) {
    const float* xc = xb + c * NPIX;
    float v0 = 0, v1 = 0, v2 = 0, v3 = 0, v5 = 0, v6 = 0, v7 = 0, v8 = 0;
    float v4 = xc[0];
    if (x0) v3 = xc[-1];
    if (x2) v5 = xc[1];
    if (y0) { v1 = xc[-HWDIM]; if (x0) v0 = xc[-HWDIM - 1]; if (x2) v2 = xc[-HWDIM + 1]; }
    if (y2) { v7 = xc[HWDIM];  if (x0) v6 = xc[HWDIM - 1];  if (x2) v8 = xc[HWDIM + 1]; }
    #pragma unroll
    for (int j = 0; j < 8; ++j) {
      if (j < nloc) {
        const float* wr = &wsm[j][c * 9];
        acc[j] += v0 * wr[0] + v1 * wr[1] + v2 * wr[2] + v3 * wr[3] + v4 * wr[4]
                + v5 * wr[5] + v6 * wr[6] + v7 * wr[7] + v8 * wr[8];
      }
    }
  }
  int pix = y * HWDIM + xx;
  #pragma unroll
  for (int j = 0; j < 8; ++j) {
    if (j < nloc) {
      int o = ol[j];
      float ms = mscale[o];
      float val = acc[j] * ms;
      if (cq == 0) val += bias[o] * ms;           // bias added exactly once
      atomicAdd(&out[((size_t)b * O_CH + o) * NPIX + pix], val);
    }
  }
}

extern "C" void kernel_launch(void* const* d_in, const int* in_sizes, int n_in,
                              void* d_out, int out_size, void* d_ws, size_t ws_size,
                              hipStream_t stream) {
  const float* x      = (const float*)d_in[0];
  const float* w      = (const float*)d_in[1];
  const float* bias   = (const float*)d_in[2];
  const float* a      = (const float*)d_in[3];
  const float* b_unit = (const float*)d_in[4];
  float* out = (float*)d_out;
  char* ws = (char*)d_ws;

  // workspace layout (bytes), total ~337 KB
  int*    ghist   = (int*)   (ws);                // NHC*5*2048*4 = 327,680
  double* ssbuf   = (double*)(ws + 327680);       // 2,048      -> 329,728
  int*    kbucket = (int*)   (ws + 329728);       // 5,120      -> 334,848
  float*  mscale  = (float*) (ws + 334848);       // 1,024      -> 335,872
  int*    actlist = (int*)   (ws + 335872);       // 1,024      -> 336,896
  int*    nact    = (int*)   (ws + 336896);       // 4          -> 336,900

  hipMemsetAsync(out, 0, (size_t)out_size * 4, stream);   // inactive channels are exact zeros
  hipMemsetAsync(ghist, 0, NHC * NH * TSIZE * 4, stream);
  k_norms <<<256, 64, 0, stream>>>(w, ssbuf);
  k_table <<<256, 256, 0, stream>>>(w, a, b_unit, ssbuf, kbucket);
  k_vote2 <<<1568, 256, 0, stream>>>(x, a, b_unit, ghist);
  k_select<<<1, 256, 0, stream>>>(ghist, kbucket, mscale, actlist, nact);
  k_aconv <<<dim3(32 * 14, 32, 4), 256, 0, stream>>>(x, w, bias, mscale, actlist, nact, out);
}

// Round 6
// 296.817 us; speedup vs baseline: 6.7764x; 6.7764x over previous
//
#include <hip/hip_runtime.h>
#include <hip/hip_bf16.h>
#include <stdint.h>

typedef __attribute__((ext_vector_type(8))) short  short8;   // 8 x bf16 fragment
typedef __attribute__((ext_vector_type(4))) float  f32x4;
typedef __attribute__((ext_vector_type(4))) unsigned int u32x4;

#define C_IN  128
#define O_CH  256
#define NH    5
#define TSIZE 2048
#define HWDIM 56
#define NPIX  3136        // 56*56
#define KTOT  1152        // 128*9
#define ADIM  1161        // KTOT + 9
#define PADW  58
#define PPIX  3364        // 58*58
#define NHC   8           // global-hist copies
#define LBINS 192         // LDS hist bins per hash (spill path covers the rest)

static __device__ __forceinline__ unsigned short f2bf(float f) {
  unsigned int u = __float_as_uint(f);
  return (unsigned short)((u + 0x7fffu + ((u >> 16) & 1u)) >> 16);   // RNE
}

// ---------------- table build (fp64 decision path — verified R3/R4/R5) ----------------
__global__ void k_norms(const float* __restrict__ w, double* __restrict__ ssbuf) {
  int o = blockIdx.x, t = threadIdx.x;            // 64 threads
  double ss = 0.;
  for (int i = t; i < KTOT; i += 64) { double v = (double)w[o * KTOT + i]; ss += v * v; }
  #pragma unroll
  for (int off = 32; off > 0; off >>= 1) ss += __shfl_down(ss, off, 64);
  if (t == 0) ssbuf[o] = ss;
}

__global__ __launch_bounds__(256) void k_table(const float* __restrict__ w,
    const float* __restrict__ a, const float* __restrict__ b_unit,
    const double* __restrict__ ssbuf, int* __restrict__ kbucket) {
  int o = blockIdx.x, t = threadIdx.x;
  __shared__ double red[256];
  __shared__ double r6[6][256];
  red[t] = ssbuf[t];
  __syncthreads();
  for (int s = 128; s; s >>= 1) { if (t < s) red[t] = fmax(red[t], red[t + s]); __syncthreads(); }
  double scale = 0.99 / sqrt(red[0]);             // U / denom
  double pd0 = 0, pd1 = 0, pd2 = 0, pd3 = 0, pd4 = 0, ss2 = 0;
  for (int i = t; i < KTOT; i += 256) {
    double wv = scale * (double)w[o * KTOT + i];
    ss2 += wv * wv;
    pd0 += wv * (double)a[0 * ADIM + i];
    pd1 += wv * (double)a[1 * ADIM + i];
    pd2 += wv * (double)a[2 * ADIM + i];
    pd3 += wv * (double)a[3 * ADIM + i];
    pd4 += wv * (double)a[4 * ADIM + i];
  }
  r6[0][t] = ss2; r6[1][t] = pd0; r6[2][t] = pd1; r6[3][t] = pd2; r6[4][t] = pd3; r6[5][t] = pd4;
  __syncthreads();
  for (int s = 128; s; s >>= 1) {
    if (t < s) { for (int q = 0; q < 6; ++q) r6[q][t] += r6[q][t + s]; }
    __syncthreads();
  }
  if (t == 0) {
    double nrm = sqrt(r6[0][0]);
    double q = nrm;
    double dp[NH] = {0, 0, 0, 0, 0};
    for (int j = 0; j < 9; ++j) {
      q = q * q;                                   // nrm^2, nrm^4, ..., nrm^512
      #pragma unroll
      for (int h = 0; h < NH; ++h) dp[h] += q * (double)a[h * ADIM + KTOT + j];
    }
    #pragma unroll
    for (int h = 0; h < NH; ++h) {
      double tot = r6[1 + h][0] + dp[h] + (double)b_unit[h] * 4.0;
      int hv = (int)floor(tot * 0.25);
      int bk = hv % TSIZE; if (bk < 0) bk = -bk;
      kbucket[o * NH + h] = bk;
    }
  }
}

// ---------------- vote conv: fp32, channel-split, small LDS hist (verified R5) ----------------
__global__ __launch_bounds__(256) void k_vote2(const float* __restrict__ x,
    const float* __restrict__ a, const float* __restrict__ b_unit, int* __restrict__ ghist) {
  __shared__ float red[4][NH][64];                // [g][h][px]
  __shared__ int   lh[NH * LBINS];
  int t = threadIdx.x;
  int px = t & 63, g = t >> 6;                    // wave = one channel-group, lanes = pixels
  for (int i = t; i < NH * LBINS; i += 256) lh[i] = 0;
  int p = blockIdx.x * 64 + px;                   // 1568*64 = 100352 exact
  int bb = p / NPIX; int rem = p - bb * NPIX;
  int y = rem / HWDIM; int xx = rem - y * HWDIM;
  bool x0 = xx > 0, x2 = xx < HWDIM - 1, y0 = y > 0, y2 = y < HWDIM - 1;
  const float* xb = x + ((size_t)bb * C_IN + g * 32) * NPIX + y * HWDIM + xx;
  float acc[NH] = {0, 0, 0, 0, 0};
  for (int c = 0; c < 32; ++c) {
    const float* xc = xb + c * NPIX;
    float v0 = 0, v1 = 0, v2 = 0, v3 = 0, v5 = 0, v6 = 0, v7 = 0, v8 = 0;
    float v4 = xc[0];
    if (x0) v3 = xc[-1];
    if (x2) v5 = xc[1];
    if (y0) { v1 = xc[-HWDIM]; if (x0) v0 = xc[-HWDIM - 1]; if (x2) v2 = xc[-HWDIM + 1]; }
    if (y2) { v7 = xc[HWDIM];  if (x0) v6 = xc[HWDIM - 1];  if (x2) v8 = xc[HWDIM + 1]; }
    #pragma unroll
    for (int h = 0; h < NH; ++h) {
      const float* ah = a + h * ADIM + (g * 32 + c) * 9;   // uniform -> scalar loads
      acc[h] += v0 * ah[0] + v1 * ah[1] + v2 * ah[2] + v3 * ah[3] + v4 * ah[4]
              + v5 * ah[5] + v6 * ah[6] + v7 * ah[7] + v8 * ah[8];
    }
  }
  #pragma unroll
  for (int h = 0; h < NH; ++h) red[g][h][px] = acc[h];
  __syncthreads();
  int* gh = ghist + (blockIdx.x & (NHC - 1)) * NH * TSIZE;
  if (g == 0) {                                   // threads 0..63 finalize their pixel
    #pragma unroll
    for (int h = 0; h < NH; ++h) {
      float s = red[0][h][px] + red[1][h][px] + red[2][h][px] + red[3][h][px];
      const float* ah = a + h * ADIM + KTOT;      // appended 0.5 channel (zero pad ring)
      float e = ah[4];
      if (x0) e += ah[3];
      if (x2) e += ah[5];
      if (y0) { e += ah[1]; if (x0) e += ah[0]; if (x2) e += ah[2]; }
      if (y2) { e += ah[7]; if (x0) e += ah[6]; if (x2) e += ah[8]; }
      s += 0.5f * e;
      int hv = (int)floorf((s + b_unit[h] * 4.0f) * 0.25f);
      int bk = hv % TSIZE; if (bk < 0) bk = -bk;
      if (bk < LBINS) atomicAdd(&lh[h * LBINS + bk], 1);
      else            atomicAdd(&gh[h * TSIZE + bk], 1);     // rare spill
    }
  }
  __syncthreads();
  for (int i = t; i < NH * LBINS; i += 256) {
    int v = lh[i];
    if (v) { int h = i / LBINS, bk = i - h * LBINS; atomicAdd(&gh[h * TSIZE + bk], v); }
  }
}

// ---------------- select + active mask (verified R5) ----------------
__global__ __launch_bounds__(256) void k_select(const int* __restrict__ ghist,
    const int* __restrict__ kbucket, float* __restrict__ mscale) {
  int t = threadIdx.x;
  __shared__ int rc[256], ri[256], sel[NH], cnt[256];
  for (int h = 0; h < NH; ++h) {
    int bc = -1, bi = 0;
    for (int i = t; i < TSIZE; i += 256) {        // ascending i + strict '>' = first-max
      int c = 0;
      #pragma unroll
      for (int k = 0; k < NHC; ++k) c += ghist[(k * NH + h) * TSIZE + i];
      if (c > bc) { bc = c; bi = i; }
    }
    rc[t] = bc; ri[t] = bi;
    __syncthreads();
    for (int s = 128; s; s >>= 1) {
      if (t < s) {
        if (rc[t + s] > rc[t] || (rc[t + s] == rc[t] && ri[t + s] < ri[t])) {
          rc[t] = rc[t + s]; ri[t] = ri[t + s];
        }
      }
      __syncthreads();
    }
    if (t == 0) sel[h] = ri[0];
    __syncthreads();
  }
  bool act = false;
  #pragma unroll
  for (int i = 0; i < NH; ++i) {
    int kb = kbucket[t * NH + i];
    #pragma unroll
    for (int j = 0; j < NH; ++j) act = act || (kb == sel[j]);
  }
  cnt[t] = act ? 1 : 0;
  __syncthreads();
  for (int s = 128; s; s >>= 1) { if (t < s) cnt[t] += cnt[t + s]; __syncthreads(); }
  int n = cnt[0];
  bool a2 = act;
  if (n == 0) { a2 = true; n = 256; }             // fallback: all active
  mscale[t] = a2 ? 256.0f / (float)n : 0.0f;
}

// ---------------- packing: plain bf16 ----------------
__global__ void k_packw1(const float* __restrict__ w, unsigned short* __restrict__ wph) {
  int idx = blockIdx.x * 256 + threadIdx.x;       // < 294912 exact
  int o = idx / KTOT; int r = idx - o * KTOT;
  int kyx = r >> 7; int c = r & 127;
  wph[idx] = f2bf(w[o * KTOT + c * 9 + kyx]);
}

__global__ __launch_bounds__(256) void k_packx1(const float* __restrict__ x, int b0,
                                                unsigned short* __restrict__ xph) {
  int bl = blockIdx.x / HWDIM; int y = blockIdx.x - bl * HWDIM;   // bl = slice-local batch
  int t = threadIdx.x;
  __shared__ unsigned short th[C_IN * 57];        // +1 pad on 56
  const float* xb = x + (size_t)((b0 + bl) * C_IN) * NPIX + y * HWDIM;
  for (int i = t; i < C_IN * HWDIM; i += 256) {
    int c = i / HWDIM; int xx = i - c * HWDIM;
    th[c * 57 + xx] = f2bf(xb[c * NPIX + xx]);
  }
  __syncthreads();
  size_t base = ((size_t)(bl * PADW + y + 1) * PADW + 1) * C_IN;
  for (int i = t; i < C_IN * HWDIM; i += 256) {
    int xx = i >> 7; int c = i & 127;
    xph[base + xx * C_IN + c] = th[c * 57 + xx];
  }
}

// ---------------- main conv: plain-bf16 implicit GEMM (structure verified R4) ----------------
__global__ __launch_bounds__(256) void k_gemm1(
    const unsigned short* __restrict__ xph, const unsigned short* __restrict__ wph,
    const float* __restrict__ bias, const float* __restrict__ mscale,
    float* __restrict__ out, int b0) {
  int mtile = blockIdx.x >> 1;                    // M-tiles of 128 pixels (slice-local)
  int ntile = blockIdx.x & 1;                     // 2 N-tiles of 128 out-channels
  int tid = threadIdx.x;
  int lane = tid & 63, wv = tid >> 6;
  int wr = wv >> 1, wc = wv & 1;                  // 2x2 wave grid, 64x64 each
  __shared__ __attribute__((aligned(16))) unsigned short As[128 * 64];
  __shared__ __attribute__((aligned(16))) unsigned short Bs[128 * 64];
  int baseA[4], baseB[4];
  #pragma unroll
  for (int j = 0; j < 4; ++j) {
    int g = j * 256 + tid;                        // 0..1023 : (m, k8) slots
    int mloc = g >> 3, k8 = (g & 7) * 8;
    int mg = mtile * 128 + mloc;
    int bb = (unsigned)mg / NPIX; int rem = mg - bb * NPIX;
    int y = (unsigned)rem / HWDIM; int xx = rem - y * HWDIM;
    baseA[j] = ((bb * PPIX + y * PADW + xx) << 7) + k8;     // padded-x element offset
    baseB[j] = (ntile * 128 + mloc) * KTOT + k8;            // w^T element offset
  }
  f32x4 acc[4][4];
  #pragma unroll
  for (int mi = 0; mi < 4; ++mi)
    #pragma unroll
    for (int ni = 0; ni < 4; ++ni) acc[mi][ni] = (f32x4){0.f, 0.f, 0.f, 0.f};

  for (int t = 0; t < 18; ++t) {                  // K = 1152 = 9 taps * 2 c-halves of 64
    int kyx = t >> 1;
    int ky = kyx / 3, kx = kyx - ky * 3;
    int koff = ((ky * PADW + kx) << 7) + ((t & 1) << 6);
    u32x4 av[4], bv[4];
    #pragma unroll
    for (int j = 0; j < 4; ++j) {
      av[j] = *(const u32x4*)(xph + baseA[j] + koff);
      bv[j] = *(const u32x4*)(wph + baseB[j] + t * 64);
    }
    __syncthreads();
    #pragma unroll
    for (int j = 0; j < 4; ++j) {
      *(u32x4*)&As[(j * 256 + tid) * 8] = av[j];
      *(u32x4*)&Bs[(j * 256 + tid) * 8] = bv[j];
    }
    __syncthreads();
    #pragma unroll
    for (int kk = 0; kk < 64; kk += 32) {
      int kc = kk + ((lane >> 4) << 3);
      int ar = lane & 15;
      short8 af[4], bf8[4];
      #pragma unroll
      for (int mi = 0; mi < 4; ++mi) af[mi]  = *(const short8*)&As[(wr * 64 + mi * 16 + ar) * 64 + kc];
      #pragma unroll
      for (int ni = 0; ni < 4; ++ni) bf8[ni] = *(const short8*)&Bs[(wc * 64 + ni * 16 + ar) * 64 + kc];
      #pragma unroll
      for (int mi = 0; mi < 4; ++mi)
        #pragma unroll
        for (int ni = 0; ni < 4; ++ni)
          acc[mi][ni] = __builtin_amdgcn_mfma_f32_16x16x32_bf16(af[mi], bf8[ni], acc[mi][ni], 0, 0, 0);
    }
  }
  // epilogue: D col = lane&15 (o), row = (lane>>4)*4+j (m)  [m89-verified layout]
  int r4 = (lane >> 4) << 2;
  int cn = lane & 15;
  #pragma unroll
  for (int ni = 0; ni < 4; ++ni) {
    int o = ntile * 128 + wc * 64 + ni * 16 + cn;
    float ms = mscale[o], bi = bias[o];
    #pragma unroll
    for (int mi = 0; mi < 4; ++mi) {
      int mg = mtile * 128 + wr * 64 + mi * 16 + r4;
      int bb = (unsigned)mg / NPIX; int pix = mg - bb * NPIX;   // mg%4==0, NPIX%4==0: vec never crosses batch
      f32x4 v;
      #pragma unroll
      for (int j = 0; j < 4; ++j) v[j] = (acc[mi][ni][j] + bi) * ms;
      *(f32x4*)(out + (size_t)(((b0 + bb) << 8) + o) * NPIX + pix) = v;
    }
  }
}

// ---------------- fallback value path (R3-verified): fp32 direct conv ----------------
__global__ __launch_bounds__(256) void k_dconv(const float* __restrict__ x,
    const float* __restrict__ w, const float* __restrict__ bias,
    const float* __restrict__ mscale, float* __restrict__ out) {
  int bid = blockIdx.x;
  int yq = bid % 14; int rem = bid / 14;
  int o = rem & 255; int b = rem >> 8;
  __shared__ float wsm[KTOT];
  for (int i = threadIdx.x; i < KTOT; i += 256) wsm[i] = w[o * KTOT + i];
  __syncthreads();
  int t = threadIdx.x;
  if (t >= 224) return;
  int y = yq * 4 + t / HWDIM;
  int xx = t % HWDIM;
  const float* xb = x + (size_t)b * C_IN * NPIX + y * HWDIM + xx;
  float acc = 0.f;
  bool y0 = y > 0, y2 = y < HWDIM - 1, x0 = xx > 0, x2 = xx < HWDIM - 1;
  for (int c = 0; c < C_IN; ++c) {
    const float* xc = xb + c * NPIX;
    const float* wc9 = wsm + c * 9;
    float s = xc[0] * wc9[4];
    if (x0) s += xc[-1] * wc9[3];
    if (x2) s += xc[1] * wc9[5];
    if (y0) { s += xc[-HWDIM] * wc9[1]; if (x0) s += xc[-HWDIM - 1] * wc9[0]; if (x2) s += xc[-HWDIM + 1] * wc9[2]; }
    if (y2) { s += xc[HWDIM] * wc9[7];  if (x0) s += xc[HWDIM - 1] * wc9[6];  if (x2) s += xc[HWDIM + 1] * wc9[8]; }
    acc += s;
  }
  out[((size_t)b * O_CH + o) * NPIX + y * HWDIM + xx] = (acc + bias[o]) * mscale[o];
}

extern "C" void kernel_launch(void* const* d_in, const int* in_sizes, int n_in,
                              void* d_out, int out_size, void* d_ws, size_t ws_size,
                              hipStream_t stream) {
  const float* x      = (const float*)d_in[0];
  const float* w      = (const float*)d_in[1];
  const float* bias   = (const float*)d_in[2];
  const float* a      = (const float*)d_in[3];
  const float* b_unit = (const float*)d_in[4];
  float* out = (float*)d_out;
  char* ws = (char*)d_ws;

  // small fixed region (bytes)
  int*    ghist   = (int*)   (ws);                // NHC*5*2048*4 = 327,680
  double* ssbuf   = (double*)(ws + 327680);       // 2,048      -> 329,728
  int*    kbucket = (int*)   (ws + 329728);       // 5,120      -> 334,848
  float*  mscale  = (float*) (ws + 334848);       // 1,024      -> 335,872
  const size_t SMALL = 337920;                    // rounded

  hipMemsetAsync(ghist, 0, NHC * NH * TSIZE * 4, stream);
  k_norms <<<256, 64, 0, stream>>>(w, ssbuf);
  k_table <<<256, 256, 0, stream>>>(w, a, b_unit, ssbuf, kbucket);
  k_vote2 <<<1568, 256, 0, stream>>>(x, a, b_unit, ghist);
  k_select<<<1, 256, 0, stream>>>(ghist, kbucket, mscale);

  // ws-adaptive batch slicing for the bf16 GEMM path
  const size_t WPT = 589824;                      // 256*1152*2
  const size_t XPB = 861184;                      // 3364*128*2 per batch
  int NB = 0;
  for (int nb = 32; nb >= 2; nb -= 2)
    if (SMALL + WPT + (size_t)nb * XPB <= ws_size) { NB = nb; break; }

  if (NB == 0) {                                  // ws too small: verified fallback
    k_dconv<<<32 * 256 * 14, 256, 0, stream>>>(x, w, bias, mscale, out);
    return;
  }

  unsigned short* wph = (unsigned short*)(ws + SMALL);
  unsigned short* xph = (unsigned short*)(ws + SMALL + WPT);

  k_packw1<<<1152, 256, 0, stream>>>(w, wph);
  hipMemsetAsync(xph, 0, (size_t)NB * XPB, stream);   // zero pad ring; interiors rewritten per slice

  for (int b0 = 0; b0 < 32; b0 += NB) {
    int nb = NB < (32 - b0) ? NB : (32 - b0);     // even (NB even, 32 even)
    k_packx1<<<nb * HWDIM, 256, 0, stream>>>(x, b0, xph);
    int mtiles = nb * NPIX / 128;                 // nb even -> exact
    k_gemm1<<<mtiles * 2, 256, 0, stream>>>(xph, wph, bias, mscale, out, b0);
  }
}

// Round 7
// 275.602 us; speedup vs baseline: 7.2980x; 1.0770x over previous
//
#include <hip/hip_runtime.h>
#include <hip/hip_bf16.h>
#include <stdint.h>

typedef __attribute__((ext_vector_type(8))) short  short8;   // 8 x bf16 fragment
typedef __attribute__((ext_vector_type(4))) float  f32x4;
typedef __attribute__((ext_vector_type(4))) unsigned int u32x4;

#define C_IN  128
#define O_CH  256
#define NH    5
#define TSIZE 2048
#define HWDIM 56
#define NPIX  3136        // 56*56
#define KTOT  1152        // 128*9
#define ADIM  1161        // KTOT + 9
#define PADW  58
#define PPIX  3364        // 58*58
#define NHC   8           // global-hist copies
#define LBINS 192         // LDS hist bins per hash (spill path covers the rest)

static __device__ __forceinline__ unsigned short f2bf(float f) {
  unsigned int u = __float_as_uint(f);
  return (unsigned short)((u + 0x7fffu + ((u >> 16) & 1u)) >> 16);   // RNE
}

// ---------------- table build (fp64 decision path — verified R3/R4/R5) ----------------
__global__ void k_norms(const float* __restrict__ w, double* __restrict__ ssbuf) {
  int o = blockIdx.x, t = threadIdx.x;            // 64 threads
  double ss = 0.;
  for (int i = t; i < KTOT; i += 64) { double v = (double)w[o * KTOT + i]; ss += v * v; }
  #pragma unroll
  for (int off = 32; off > 0; off >>= 1) ss += __shfl_down(ss, off, 64);
  if (t == 0) ssbuf[o] = ss;
}

__global__ __launch_bounds__(256) void k_table(const float* __restrict__ w,
    const float* __restrict__ a, const float* __restrict__ b_unit,
    const double* __restrict__ ssbuf, int* __restrict__ kbucket) {
  int o = blockIdx.x, t = threadIdx.x;
  __shared__ double red[256];
  __shared__ double r6[6][256];
  red[t] = ssbuf[t];
  __syncthreads();
  for (int s = 128; s; s >>= 1) { if (t < s) red[t] = fmax(red[t], red[t + s]); __syncthreads(); }
  double scale = 0.99 / sqrt(red[0]);             // U / denom
  double pd0 = 0, pd1 = 0, pd2 = 0, pd3 = 0, pd4 = 0, ss2 = 0;
  for (int i = t; i < KTOT; i += 256) {
    double wv = scale * (double)w[o * KTOT + i];
    ss2 += wv * wv;
    pd0 += wv * (double)a[0 * ADIM + i];
    pd1 += wv * (double)a[1 * ADIM + i];
    pd2 += wv * (double)a[2 * ADIM + i];
    pd3 += wv * (double)a[3 * ADIM + i];
    pd4 += wv * (double)a[4 * ADIM + i];
  }
  r6[0][t] = ss2; r6[1][t] = pd0; r6[2][t] = pd1; r6[3][t] = pd2; r6[4][t] = pd3; r6[5][t] = pd4;
  __syncthreads();
  for (int s = 128; s; s >>= 1) {
    if (t < s) { for (int q = 0; q < 6; ++q) r6[q][t] += r6[q][t + s]; }
    __syncthreads();
  }
  if (t == 0) {
    double nrm = sqrt(r6[0][0]);
    double q = nrm;
    double dp[NH] = {0, 0, 0, 0, 0};
    for (int j = 0; j < 9; ++j) {
      q = q * q;                                   // nrm^2, nrm^4, ..., nrm^512
      #pragma unroll
      for (int h = 0; h < NH; ++h) dp[h] += q * (double)a[h * ADIM + KTOT + j];
    }
    #pragma unroll
    for (int h = 0; h < NH; ++h) {
      double tot = r6[1 + h][0] + dp[h] + (double)b_unit[h] * 4.0;
      int hv = (int)floor(tot * 0.25);
      int bk = hv % TSIZE; if (bk < 0) bk = -bk;
      kbucket[o * NH + h] = bk;
    }
  }
}

// ---------------- vote conv: fp32, channel-split, small LDS hist (verified R5) ----------------
__global__ __launch_bounds__(256) void k_vote2(const float* __restrict__ x,
    const float* __restrict__ a, const float* __restrict__ b_unit, int* __restrict__ ghist) {
  __shared__ float red[4][NH][64];                // [g][h][px]
  __shared__ int   lh[NH * LBINS];
  int t = threadIdx.x;
  int px = t & 63, g = t >> 6;                    // wave = one channel-group, lanes = pixels
  for (int i = t; i < NH * LBINS; i += 256) lh[i] = 0;
  int p = blockIdx.x * 64 + px;                   // 1568*64 = 100352 exact
  int bb = p / NPIX; int rem = p - bb * NPIX;
  int y = rem / HWDIM; int xx = rem - y * HWDIM;
  bool x0 = xx > 0, x2 = xx < HWDIM - 1, y0 = y > 0, y2 = y < HWDIM - 1;
  const float* xb = x + ((size_t)bb * C_IN + g * 32) * NPIX + y * HWDIM + xx;
  float acc[NH] = {0, 0, 0, 0, 0};
  for (int c = 0; c < 32; ++c) {
    const float* xc = xb + c * NPIX;
    float v0 = 0, v1 = 0, v2 = 0, v3 = 0, v5 = 0, v6 = 0, v7 = 0, v8 = 0;
    float v4 = xc[0];
    if (x0) v3 = xc[-1];
    if (x2) v5 = xc[1];
    if (y0) { v1 = xc[-HWDIM]; if (x0) v0 = xc[-HWDIM - 1]; if (x2) v2 = xc[-HWDIM + 1]; }
    if (y2) { v7 = xc[HWDIM];  if (x0) v6 = xc[HWDIM - 1];  if (x2) v8 = xc[HWDIM + 1]; }
    #pragma unroll
    for (int h = 0; h < NH; ++h) {
      const float* ah = a + h * ADIM + (g * 32 + c) * 9;   // uniform -> scalar loads
      acc[h] += v0 * ah[0] + v1 * ah[1] + v2 * ah[2] + v3 * ah[3] + v4 * ah[4]
              + v5 * ah[5] + v6 * ah[6] + v7 * ah[7] + v8 * ah[8];
    }
  }
  #pragma unroll
  for (int h = 0; h < NH; ++h) red[g][h][px] = acc[h];
  __syncthreads();
  int* gh = ghist + (blockIdx.x & (NHC - 1)) * NH * TSIZE;
  if (g == 0) {                                   // threads 0..63 finalize their pixel
    #pragma unroll
    for (int h = 0; h < NH; ++h) {
      float s = red[0][h][px] + red[1][h][px] + red[2][h][px] + red[3][h][px];
      const float* ah = a + h * ADIM + KTOT;      // appended 0.5 channel (zero pad ring)
      float e = ah[4];
      if (x0) e += ah[3];
      if (x2) e += ah[5];
      if (y0) { e += ah[1]; if (x0) e += ah[0]; if (x2) e += ah[2]; }
      if (y2) { e += ah[7]; if (x0) e += ah[6]; if (x2) e += ah[8]; }
      s += 0.5f * e;
      int hv = (int)floorf((s + b_unit[h] * 4.0f) * 0.25f);
      int bk = hv % TSIZE; if (bk < 0) bk = -bk;
      if (bk < LBINS) atomicAdd(&lh[h * LBINS + bk], 1);
      else            atomicAdd(&gh[h * TSIZE + bk], 1);     // rare spill
    }
  }
  __syncthreads();
  for (int i = t; i < NH * LBINS; i += 256) {
    int v = lh[i];
    if (v) { int h = i / LBINS, bk = i - h * LBINS; atomicAdd(&gh[h * TSIZE + bk], v); }
  }
}

// ---------------- select + active mask (verified R5) ----------------
__global__ __launch_bounds__(256) void k_select(const int* __restrict__ ghist,
    const int* __restrict__ kbucket, float* __restrict__ mscale) {
  int t = threadIdx.x;
  __shared__ int rc[256], ri[256], sel[NH], cnt[256];
  for (int h = 0; h < NH; ++h) {
    int bc = -1, bi = 0;
    for (int i = t; i < TSIZE; i += 256) {        // ascending i + strict '>' = first-max
      int c = 0;
      #pragma unroll
      for (int k = 0; k < NHC; ++k) c += ghist[(k * NH + h) * TSIZE + i];
      if (c > bc) { bc = c; bi = i; }
    }
    rc[t] = bc; ri[t] = bi;
    __syncthreads();
    for (int s = 128; s; s >>= 1) {
      if (t < s) {
        if (rc[t + s] > rc[t] || (rc[t + s] == rc[t] && ri[t + s] < ri[t])) {
          rc[t] = rc[t + s]; ri[t] = ri[t + s];
        }
      }
      __syncthreads();
    }
    if (t == 0) sel[h] = ri[0];
    __syncthreads();
  }
  bool act = false;
  #pragma unroll
  for (int i = 0; i < NH; ++i) {
    int kb = kbucket[t * NH + i];
    #pragma unroll
    for (int j = 0; j < NH; ++j) act = act || (kb == sel[j]);
  }
  cnt[t] = act ? 1 : 0;
  __syncthreads();
  for (int s = 128; s; s >>= 1) { if (t < s) cnt[t] += cnt[t + s]; __syncthreads(); }
  int n = cnt[0];
  bool a2 = act;
  if (n == 0) { a2 = true; n = 256; }             // fallback: all active
  mscale[t] = a2 ? 256.0f / (float)n : 0.0f;
}

// ---------------- packing: plain bf16 ----------------
__global__ void k_packw1(const float* __restrict__ w, unsigned short* __restrict__ wph) {
  int idx = blockIdx.x * 256 + threadIdx.x;       // < 294912 exact
  int o = idx / KTOT; int r = idx - o * KTOT;
  int kyx = r >> 7; int c = r & 127;
  wph[idx] = f2bf(w[o * KTOT + c * 9 + kyx]);
}

__global__ __launch_bounds__(256) void k_packx1(const float* __restrict__ x, int b0,
                                                unsigned short* __restrict__ xph) {
  int bl = blockIdx.x / HWDIM; int y = blockIdx.x - bl * HWDIM;   // bl = slice-local batch
  int t = threadIdx.x;
  __shared__ unsigned short th[C_IN * 57];        // +1 pad on 56
  const float* xb = x + (size_t)((b0 + bl) * C_IN) * NPIX + y * HWDIM;
  for (int i = t; i < C_IN * HWDIM; i += 256) {
    int c = i / HWDIM; int xx = i - c * HWDIM;
    th[c * 57 + xx] = f2bf(xb[c * NPIX + xx]);
  }
  __syncthreads();
  size_t base = ((size_t)(bl * PADW + y + 1) * PADW + 1) * C_IN;
  for (int i = t; i < C_IN * HWDIM; i += 256) {
    int xx = i >> 7; int c = i & 127;
    xph[base + xx * C_IN + c] = th[c * 57 + xx];
  }
}

// ---------------- main conv: bf16 implicit GEMM, XOR-swizzled LDS + 2-phase prefetch ----------------
__global__ __launch_bounds__(256) void k_gemm1(
    const unsigned short* __restrict__ xph, const unsigned short* __restrict__ wph,
    const float* __restrict__ bias, const float* __restrict__ mscale,
    float* __restrict__ out, int b0) {
  int mtile = blockIdx.x >> 1;                    // M-tiles of 128 pixels (slice-local)
  int ntile = blockIdx.x & 1;                     // 2 N-tiles of 128 out-channels
  int tid = threadIdx.x;
  int lane = tid & 63, wv = tid >> 6;
  int wr = wv >> 1, wc = wv & 1;                  // 2x2 wave grid, 64x64 each
  __shared__ __attribute__((aligned(16))) unsigned short As[128 * 64];
  __shared__ __attribute__((aligned(16))) unsigned short Bs[128 * 64];
  int baseA[4], baseB[4], soff[4];
  #pragma unroll
  for (int j = 0; j < 4; ++j) {
    int g = j * 256 + tid;                        // 0..1023 : (row, chunk) slots
    int row = g >> 3, ch = g & 7;
    int mg = mtile * 128 + row;
    int bb = (unsigned)mg / NPIX; int rem = mg - bb * NPIX;
    int y = (unsigned)rem / HWDIM; int xx = rem - y * HWDIM;
    baseA[j] = ((bb * PPIX + y * PADW + xx) << 7) + ch * 8;   // padded-x element offset
    baseB[j] = (ntile * 128 + row) * KTOT + ch * 8;           // w^T element offset
    soff[j]  = row * 64 + ((ch ^ (row & 7)) << 3);            // XOR-swizzled LDS offset
  }
  f32x4 acc[4][4];
  #pragma unroll
  for (int mi = 0; mi < 4; ++mi)
    #pragma unroll
    for (int ni = 0; ni < 4; ++ni) acc[mi][ni] = (f32x4){0.f, 0.f, 0.f, 0.f};

  // read-side swizzled addresses (row&7 == lane&7 uniformly: wr*64, wc*64, mi*16, ni*16 all ≡ 0 mod 8)
  int ar = lane & 15, hi = lane >> 4, sx = lane & 7;

  u32x4 av[4], bv[4];
  #pragma unroll
  for (int j = 0; j < 4; ++j) {                   // prologue: tile t=0 (tap ky=0,kx=0, half 0)
    av[j] = *(const u32x4*)(xph + baseA[j]);
    bv[j] = *(const u32x4*)(wph + baseB[j]);
  }

  for (int t = 0; t < 18; ++t) {                  // K = 1152 = 9 taps * 2 c-halves of 64
    __syncthreads();                              // previous compute done reading LDS
    #pragma unroll
    for (int j = 0; j < 4; ++j) {
      *(u32x4*)&As[soff[j]] = av[j];
      *(u32x4*)&Bs[soff[j]] = bv[j];
    }
    __syncthreads();
    if (t < 17) {                                 // issue next tile's loads; retire under MFMAs
      int tn = t + 1;
      int kyx = tn >> 1;
      int ky = kyx / 3, kx = kyx - ky * 3;
      int koff = ((ky * PADW + kx) << 7) + ((tn & 1) << 6);
      #pragma unroll
      for (int j = 0; j < 4; ++j) {
        av[j] = *(const u32x4*)(xph + baseA[j] + koff);
        bv[j] = *(const u32x4*)(wph + baseB[j] + tn * 64);
      }
    }
    #pragma unroll
    for (int kk = 0; kk < 64; kk += 32) {
      int ch = (kk >> 3) + hi;                    // chunk column of this fragment
      int col = ((ch ^ sx) << 3);                 // swizzled element column
      short8 af[4], bf8[4];
      #pragma unroll
      for (int mi = 0; mi < 4; ++mi) af[mi]  = *(const short8*)&As[(wr * 64 + mi * 16 + ar) * 64 + col];
      #pragma unroll
      for (int ni = 0; ni < 4; ++ni) bf8[ni] = *(const short8*)&Bs[(wc * 64 + ni * 16 + ar) * 64 + col];
      #pragma unroll
      for (int mi = 0; mi < 4; ++mi)
        #pragma unroll
        for (int ni = 0; ni < 4; ++ni)
          acc[mi][ni] = __builtin_amdgcn_mfma_f32_16x16x32_bf16(af[mi], bf8[ni], acc[mi][ni], 0, 0, 0);
    }
  }
  // epilogue: D col = lane&15 (o), row = (lane>>4)*4+j (m)  [m89-verified layout]
  int r4 = hi << 2;
  int cn = ar;
  #pragma unroll
  for (int ni = 0; ni < 4; ++ni) {
    int o = ntile * 128 + wc * 64 + ni * 16 + cn;
    float ms = mscale[o], bi = bias[o];
    #pragma unroll
    for (int mi = 0; mi < 4; ++mi) {
      int mg = mtile * 128 + wr * 64 + mi * 16 + r4;
      int bb = (unsigned)mg / NPIX; int pix = mg - bb * NPIX;   // mg%4==0, NPIX%4==0: vec never crosses batch
      f32x4 v;
      #pragma unroll
      for (int j = 0; j < 4; ++j) v[j] = (acc[mi][ni][j] + bi) * ms;
      *(f32x4*)(out + (size_t)(((b0 + bb) << 8) + o) * NPIX + pix) = v;
    }
  }
}

// ---------------- fallback value path (R3-verified): fp32 direct conv ----------------
__global__ __launch_bounds__(256) void k_dconv(const float* __restrict__ x,
    const float* __restrict__ w, const float* __restrict__ bias,
    const float* __restrict__ mscale, float* __restrict__ out) {
  int bid = blockIdx.x;
  int yq = bid % 14; int rem = bid / 14;
  int o = rem & 255; int b = rem >> 8;
  __shared__ float wsm[KTOT];
  for (int i = threadIdx.x; i < KTOT; i += 256) wsm[i] = w[o * KTOT + i];
  __syncthreads();
  int t = threadIdx.x;
  if (t >= 224) return;
  int y = yq * 4 + t / HWDIM;
  int xx = t % HWDIM;
  const float* xb = x + (size_t)b * C_IN * NPIX + y * HWDIM + xx;
  float acc = 0.f;
  bool y0 = y > 0, y2 = y < HWDIM - 1, x0 = xx > 0, x2 = xx < HWDIM - 1;
  for (int c = 0; c < C_IN; ++c) {
    const float* xc = xb + c * NPIX;
    const float* wc9 = wsm + c * 9;
    float s = xc[0] * wc9[4];
    if (x0) s += xc[-1] * wc9[3];
    if (x2) s += xc[1] * wc9[5];
    if (y0) { s += xc[-HWDIM] * wc9[1]; if (x0) s += xc[-HWDIM - 1] * wc9[0]; if (x2) s += xc[-HWDIM + 1] * wc9[2]; }
    if (y2) { s += xc[HWDIM] * wc9[7];  if (x0) s += xc[HWDIM - 1] * wc9[6];  if (x2) s += xc[HWDIM + 1] * wc9[8]; }
    acc += s;
  }
  out[((size_t)b * O_CH + o) * NPIX + y * HWDIM + xx] = (acc + bias[o]) * mscale[o];
}

extern "C" void kernel_launch(void* const* d_in, const int* in_sizes, int n_in,
                              void* d_out, int out_size, void* d_ws, size_t ws_size,
                              hipStream_t stream) {
  const float* x      = (const float*)d_in[0];
  const float* w      = (const float*)d_in[1];
  const float* bias   = (const float*)d_in[2];
  const float* a      = (const float*)d_in[3];
  const float* b_unit = (const float*)d_in[4];
  float* out = (float*)d_out;
  char* ws = (char*)d_ws;

  // small fixed region (bytes)
  int*    ghist   = (int*)   (ws);                // NHC*5*2048*4 = 327,680
  double* ssbuf   = (double*)(ws + 327680);       // 2,048      -> 329,728
  int*    kbucket = (int*)   (ws + 329728);       // 5,120      -> 334,848
  float*  mscale  = (float*) (ws + 334848);       // 1,024      -> 335,872
  const size_t SMALL = 337920;                    // rounded

  hipMemsetAsync(ghist, 0, NHC * NH * TSIZE * 4, stream);
  k_norms <<<256, 64, 0, stream>>>(w, ssbuf);
  k_table <<<256, 256, 0, stream>>>(w, a, b_unit, ssbuf, kbucket);
  k_vote2 <<<1568, 256, 0, stream>>>(x, a, b_unit, ghist);
  k_select<<<1, 256, 0, stream>>>(ghist, kbucket, mscale);

  // ws-adaptive batch slicing for the bf16 GEMM path
  const size_t WPT = 589824;                      // 256*1152*2
  const size_t XPB = 861184;                      // 3364*128*2 per batch
  int NB = 0;
  for (int nb = 32; nb >= 2; nb -= 2)
    if (SMALL + WPT + (size_t)nb * XPB <= ws_size) { NB = nb; break; }

  if (NB == 0) {                                  // ws too small: verified fallback
    k_dconv<<<32 * 256 * 14, 256, 0, stream>>>(x, w, bias, mscale, out);
    return;
  }

  unsigned short* wph = (unsigned short*)(ws + SMALL);
  unsigned short* xph = (unsigned short*)(ws + SMALL + WPT);

  k_packw1<<<1152, 256, 0, stream>>>(w, wph);
  hipMemsetAsync(xph, 0, (size_t)NB * XPB, stream);   // zero pad ring; interiors rewritten per slice

  for (int b0 = 0; b0 < 32; b0 += NB) {
    int nb = NB < (32 - b0) ? NB : (32 - b0);     // even (NB even, 32 even)
    k_packx1<<<nb * HWDIM, 256, 0, stream>>>(x, b0, xph);
    int mtiles = nb * NPIX / 128;                 // nb even -> exact
    k_gemm1<<<mtiles * 2, 256, 0, stream>>>(xph, wph, bias, mscale, out, b0);
  }
}

// Round 8
// 231.265 us; speedup vs baseline: 8.6972x; 1.1917x over previous
//
#include <hip/hip_runtime.h>
#include <hip/hip_bf16.h>
#include <stdint.h>

typedef __attribute__((ext_vector_type(8))) short  short8;   // 8 x bf16 fragment
typedef __attribute__((ext_vector_type(4))) float  f32x4;
typedef __attribute__((ext_vector_type(4))) unsigned int u32x4;

#define C_IN  128
#define O_CH  256
#define NH    5
#define TSIZE 2048
#define HWDIM 56
#define NPIX  3136        // 56*56
#define MTOT  100352      // 32*3136
#define KTOT  1152        // 128*9
#define ADIM  1161        // KTOT + 9
#define PADW  58
#define PPIX  3364        // 58*58
#define NHC   8           // global-hist copies
#define LBINS 192         // LDS hist bins per hash (spill path covers the rest)

static __device__ __forceinline__ unsigned short f2bf(float f) {
  unsigned int u = __float_as_uint(f);
  return (unsigned short)((u + 0x7fffu + ((u >> 16) & 1u)) >> 16);   // RNE
}

// ---------------- table build (fp64 decision path — verified R3..R7) ----------------
__global__ void k_norms(const float* __restrict__ w, double* __restrict__ ssbuf) {
  int o = blockIdx.x, t = threadIdx.x;            // 64 threads
  double ss = 0.;
  for (int i = t; i < KTOT; i += 64) { double v = (double)w[o * KTOT + i]; ss += v * v; }
  #pragma unroll
  for (int off = 32; off > 0; off >>= 1) ss += __shfl_down(ss, off, 64);
  if (t == 0) ssbuf[o] = ss;
}

__global__ __launch_bounds__(256) void k_table(const float* __restrict__ w,
    const float* __restrict__ a, const float* __restrict__ b_unit,
    const double* __restrict__ ssbuf, int* __restrict__ kbucket) {
  int o = blockIdx.x, t = threadIdx.x;
  __shared__ double red[256];
  __shared__ double r6[6][256];
  red[t] = ssbuf[t];
  __syncthreads();
  for (int s = 128; s; s >>= 1) { if (t < s) red[t] = fmax(red[t], red[t + s]); __syncthreads(); }
  double scale = 0.99 / sqrt(red[0]);             // U / denom
  double pd0 = 0, pd1 = 0, pd2 = 0, pd3 = 0, pd4 = 0, ss2 = 0;
  for (int i = t; i < KTOT; i += 256) {
    double wv = scale * (double)w[o * KTOT + i];
    ss2 += wv * wv;
    pd0 += wv * (double)a[0 * ADIM + i];
    pd1 += wv * (double)a[1 * ADIM + i];
    pd2 += wv * (double)a[2 * ADIM + i];
    pd3 += wv * (double)a[3 * ADIM + i];
    pd4 += wv * (double)a[4 * ADIM + i];
  }
  r6[0][t] = ss2; r6[1][t] = pd0; r6[2][t] = pd1; r6[3][t] = pd2; r6[4][t] = pd3; r6[5][t] = pd4;
  __syncthreads();
  for (int s = 128; s; s >>= 1) {
    if (t < s) { for (int q = 0; q < 6; ++q) r6[q][t] += r6[q][t + s]; }
    __syncthreads();
  }
  if (t == 0) {
    double nrm = sqrt(r6[0][0]);
    double q = nrm;
    double dp[NH] = {0, 0, 0, 0, 0};
    for (int j = 0; j < 9; ++j) {
      q = q * q;                                   // nrm^2, nrm^4, ..., nrm^512
      #pragma unroll
      for (int h = 0; h < NH; ++h) dp[h] += q * (double)a[h * ADIM + KTOT + j];
    }
    #pragma unroll
    for (int h = 0; h < NH; ++h) {
      double tot = r6[1 + h][0] + dp[h] + (double)b_unit[h] * 4.0;
      int hv = (int)floor(tot * 0.25);
      int bk = hv % TSIZE; if (bk < 0) bk = -bk;
      kbucket[o * NH + h] = bk;
    }
  }
}

// ---------------- a repack: apk[c][48] = a[h*ADIM + c*9 + k] at [c*48 + h*9 + k] ----------------
__global__ void k_packa(const float* __restrict__ a, float* __restrict__ apk) {
  int i = blockIdx.x * 256 + threadIdx.x;         // 128*45 = 5760
  if (i >= C_IN * 45) return;
  int c = i / 45, r = i - c * 45;                 // r = h*9+k
  int h = r / 9, k = r - h * 9;
  apk[c * 48 + r] = a[h * ADIM + c * 9 + k];
}

// ---------------- vote pass 1: block-uniform channel group -> s_load coeffs ----------------
__global__ __launch_bounds__(256) void k_vote3a(const float* __restrict__ x,
    const float* __restrict__ apk, float* __restrict__ pdot) {
  int g = blockIdx.y;                             // channel group 0..3 (wave-uniform!)
  int t = threadIdx.x;
  int p = blockIdx.x * 256 + t;                   // 392*256 = 100352 exact
  int bb = p / NPIX; int rem = p - bb * NPIX;
  int y = rem / HWDIM; int xx = rem - y * HWDIM;
  bool x0 = xx > 0, x2 = xx < HWDIM - 1, y0 = y > 0, y2 = y < HWDIM - 1;
  const float* xb = x + ((size_t)bb * C_IN + g * 32) * NPIX + y * HWDIM + xx;
  const float* ap = apk + (g * 32) * 48;          // uniform base -> scalar loads
  float acc[NH] = {0, 0, 0, 0, 0};
  for (int c = 0; c < 32; ++c) {
    const float* xc = xb + c * NPIX;
    float v0 = 0, v1 = 0, v2 = 0, v3 = 0, v5 = 0, v6 = 0, v7 = 0, v8 = 0;
    float v4 = xc[0];
    if (x0) v3 = xc[-1];
    if (x2) v5 = xc[1];
    if (y0) { v1 = xc[-HWDIM]; if (x0) v0 = xc[-HWDIM - 1]; if (x2) v2 = xc[-HWDIM + 1]; }
    if (y2) { v7 = xc[HWDIM];  if (x0) v6 = xc[HWDIM - 1];  if (x2) v8 = xc[HWDIM + 1]; }
    const float* ac = ap + c * 48;
    #pragma unroll
    for (int h = 0; h < NH; ++h) {
      const float* ah = ac + h * 9;
      acc[h] += v0 * ah[0] + v1 * ah[1] + v2 * ah[2] + v3 * ah[3] + v4 * ah[4]
              + v5 * ah[5] + v6 * ah[6] + v7 * ah[7] + v8 * ah[8];
    }
  }
  #pragma unroll
  for (int h = 0; h < NH; ++h) pdot[((size_t)g * NH + h) * MTOT + p] = acc[h];
}

// ---------------- vote pass 2: deterministic group-sum + bin (R5 expression order) ----------------
__global__ __launch_bounds__(256) void k_vote3b(const float* __restrict__ pdot,
    const float* __restrict__ a, const float* __restrict__ b_unit, int* __restrict__ ghist) {
  __shared__ int lh[NH * LBINS];
  int t = threadIdx.x;
  for (int i = t; i < NH * LBINS; i += 256) lh[i] = 0;
  __syncthreads();
  int p = blockIdx.x * 256 + t;                   // 392*256 = 100352 exact
  int bb = p / NPIX; int rem = p - bb * NPIX;
  int y = rem / HWDIM; int xx = rem - y * HWDIM;
  bool x0 = xx > 0, x2 = xx < HWDIM - 1, y0 = y > 0, y2 = y < HWDIM - 1;
  int* gh = ghist + (blockIdx.x & (NHC - 1)) * NH * TSIZE;
  #pragma unroll
  for (int h = 0; h < NH; ++h) {
    float s = pdot[((size_t)0 * NH + h) * MTOT + p] + pdot[((size_t)1 * NH + h) * MTOT + p]
            + pdot[((size_t)2 * NH + h) * MTOT + p] + pdot[((size_t)3 * NH + h) * MTOT + p];
    const float* ah = a + h * ADIM + KTOT;        // appended 0.5 channel (zero pad ring)
    float e = ah[4];
    if (x0) e += ah[3];
    if (x2) e += ah[5];
    if (y0) { e += ah[1]; if (x0) e += ah[0]; if (x2) e += ah[2]; }
    if (y2) { e += ah[7]; if (x0) e += ah[6]; if (x2) e += ah[8]; }
    s += 0.5f * e;
    int hv = (int)floorf((s + b_unit[h] * 4.0f) * 0.25f);
    int bk = hv % TSIZE; if (bk < 0) bk = -bk;
    if (bk < LBINS) atomicAdd(&lh[h * LBINS + bk], 1);
    else            atomicAdd(&gh[h * TSIZE + bk], 1);     // rare spill
  }
  __syncthreads();
  for (int i = t; i < NH * LBINS; i += 256) {
    int v = lh[i];
    if (v) { int h = i / LBINS, bk = i - h * LBINS; atomicAdd(&gh[h * TSIZE + bk], v); }
  }
}

// ---------------- vote fallback (verified R5): single-pass, used only if ws is tiny ----------------
__global__ __launch_bounds__(256) void k_vote2(const float* __restrict__ x,
    const float* __restrict__ a, const float* __restrict__ b_unit, int* __restrict__ ghist) {
  __shared__ float red[4][NH][64];
  __shared__ int   lh[NH * LBINS];
  int t = threadIdx.x;
  int px = t & 63, g = t >> 6;
  for (int i = t; i < NH * LBINS; i += 256) lh[i] = 0;
  int p = blockIdx.x * 64 + px;
  int bb = p / NPIX; int rem = p - bb * NPIX;
  int y = rem / HWDIM; int xx = rem - y * HWDIM;
  bool x0 = xx > 0, x2 = xx < HWDIM - 1, y0 = y > 0, y2 = y < HWDIM - 1;
  const float* xb = x + ((size_t)bb * C_IN + g * 32) * NPIX + y * HWDIM + xx;
  float acc[NH] = {0, 0, 0, 0, 0};
  for (int c = 0; c < 32; ++c) {
    const float* xc = xb + c * NPIX;
    float v0 = 0, v1 = 0, v2 = 0, v3 = 0, v5 = 0, v6 = 0, v7 = 0, v8 = 0;
    float v4 = xc[0];
    if (x0) v3 = xc[-1];
    if (x2) v5 = xc[1];
    if (y0) { v1 = xc[-HWDIM]; if (x0) v0 = xc[-HWDIM - 1]; if (x2) v2 = xc[-HWDIM + 1]; }
    if (y2) { v7 = xc[HWDIM];  if (x0) v6 = xc[HWDIM - 1];  if (x2) v8 = xc[HWDIM + 1]; }
    #pragma unroll
    for (int h = 0; h < NH; ++h) {
      const float* ah = a + h * ADIM + (g * 32 + c) * 9;
      acc[h] += v0 * ah[0] + v1 * ah[1] + v2 * ah[2] + v3 * ah[3] + v4 * ah[4]
              + v5 * ah[5] + v6 * ah[6] + v7 * ah[7] + v8 * ah[8];
    }
  }
  #pragma unroll
  for (int h = 0; h < NH; ++h) red[g][h][px] = acc[h];
  __syncthreads();
  int* gh = ghist + (blockIdx.x & (NHC - 1)) * NH * TSIZE;
  if (g == 0) {
    #pragma unroll
    for (int h = 0; h < NH; ++h) {
      float s = red[0][h][px] + red[1][h][px] + red[2][h][px] + red[3][h][px];
      const float* ah = a + h * ADIM + KTOT;
      float e = ah[4];
      if (x0) e += ah[3];
      if (x2) e += ah[5];
      if (y0) { e += ah[1]; if (x0) e += ah[0]; if (x2) e += ah[2]; }
      if (y2) { e += ah[7]; if (x0) e += ah[6]; if (x2) e += ah[8]; }
      s += 0.5f * e;
      int hv = (int)floorf((s + b_unit[h] * 4.0f) * 0.25f);
      int bk = hv % TSIZE; if (bk < 0) bk = -bk;
      if (bk < LBINS) atomicAdd(&lh[h * LBINS + bk], 1);
      else            atomicAdd(&gh[h * TSIZE + bk], 1);
    }
  }
  __syncthreads();
  for (int i = t; i < NH * LBINS; i += 256) {
    int v = lh[i];
    if (v) { int h = i / LBINS, bk = i - h * LBINS; atomicAdd(&gh[h * TSIZE + bk], v); }
  }
}

// ---------------- select + active mask (verified R5) ----------------
__global__ __launch_bounds__(256) void k_select(const int* __restrict__ ghist,
    const int* __restrict__ kbucket, float* __restrict__ mscale) {
  int t = threadIdx.x;
  __shared__ int rc[256], ri[256], sel[NH], cnt[256];
  for (int h = 0; h < NH; ++h) {
    int bc = -1, bi = 0;
    for (int i = t; i < TSIZE; i += 256) {        // ascending i + strict '>' = first-max
      int c = 0;
      #pragma unroll
      for (int k = 0; k < NHC; ++k) c += ghist[(k * NH + h) * TSIZE + i];
      if (c > bc) { bc = c; bi = i; }
    }
    rc[t] = bc; ri[t] = bi;
    __syncthreads();
    for (int s = 128; s; s >>= 1) {
      if (t < s) {
        if (rc[t + s] > rc[t] || (rc[t + s] == rc[t] && ri[t + s] < ri[t])) {
          rc[t] = rc[t + s]; ri[t] = ri[t + s];
        }
      }
      __syncthreads();
    }
    if (t == 0) sel[h] = ri[0];
    __syncthreads();
  }
  bool act = false;
  #pragma unroll
  for (int i = 0; i < NH; ++i) {
    int kb = kbucket[t * NH + i];
    #pragma unroll
    for (int j = 0; j < NH; ++j) act = act || (kb == sel[j]);
  }
  cnt[t] = act ? 1 : 0;
  __syncthreads();
  for (int s = 128; s; s >>= 1) { if (t < s) cnt[t] += cnt[t + s]; __syncthreads(); }
  int n = cnt[0];
  bool a2 = act;
  if (n == 0) { a2 = true; n = 256; }             // fallback: all active
  mscale[t] = a2 ? 256.0f / (float)n : 0.0f;
}

// ---------------- packing: plain bf16 ----------------
__global__ void k_packw1(const float* __restrict__ w, unsigned short* __restrict__ wph) {
  int idx = blockIdx.x * 256 + threadIdx.x;       // < 294912 exact
  int o = idx / KTOT; int r = idx - o * KTOT;
  int kyx = r >> 7; int c = r & 127;
  wph[idx] = f2bf(w[o * KTOT + c * 9 + kyx]);
}

__global__ __launch_bounds__(256) void k_packx1(const float* __restrict__ x, int b0,
                                                unsigned short* __restrict__ xph) {
  int bl = blockIdx.x / HWDIM; int y = blockIdx.x - bl * HWDIM;   // bl = slice-local batch
  int t = threadIdx.x;
  __shared__ unsigned short th[C_IN * 57];        // +1 pad on 56
  const float* xb = x + (size_t)((b0 + bl) * C_IN) * NPIX + y * HWDIM;
  for (int i = t; i < C_IN * HWDIM; i += 256) {
    int c = i / HWDIM; int xx = i - c * HWDIM;
    th[c * 57 + xx] = f2bf(xb[c * NPIX + xx]);
  }
  __syncthreads();
  size_t base = ((size_t)(bl * PADW + y + 1) * PADW + 1) * C_IN;
  for (int i = t; i < C_IN * HWDIM; i += 256) {
    int xx = i >> 7; int c = i & 127;
    xph[base + xx * C_IN + c] = th[c * 57 + xx];
  }
}

// ---------------- pad-ring zeroing (replaces 27.6 MB memset) ----------------
__global__ __launch_bounds__(256) void k_ring(unsigned short* __restrict__ xph) {
  int r = blockIdx.x % PADW;                      // plane row 0..57
  int bl = blockIdx.x / PADW;                     // slab
  unsigned short* row = xph + ((size_t)bl * PPIX + (size_t)r * PADW) * C_IN;
  int t = threadIdx.x;
  if (r == 0 || r == PADW - 1) {
    for (int i = t; i < PADW * C_IN; i += 256) row[i] = 0;
  } else {
    if (t < 128) row[t] = 0;                      // col 0
    else row[57 * C_IN + (t - 128)] = 0;          // col 57
  }
}

// ---------------- main conv: bf16 implicit GEMM, XOR-swizzled LDS + 2-phase prefetch (R7) ----------------
__global__ __launch_bounds__(256) void k_gemm1(
    const unsigned short* __restrict__ xph, const unsigned short* __restrict__ wph,
    const float* __restrict__ bias, const float* __restrict__ mscale,
    float* __restrict__ out, int b0) {
  int mtile = blockIdx.x >> 1;                    // M-tiles of 128 pixels (slice-local)
  int ntile = blockIdx.x & 1;                     // 2 N-tiles of 128 out-channels
  int tid = threadIdx.x;
  int lane = tid & 63, wv = tid >> 6;
  int wr = wv >> 1, wc = wv & 1;                  // 2x2 wave grid, 64x64 each
  __shared__ __attribute__((aligned(16))) unsigned short As[128 * 64];
  __shared__ __attribute__((aligned(16))) unsigned short Bs[128 * 64];
  int baseA[4], baseB[4], soff[4];
  #pragma unroll
  for (int j = 0; j < 4; ++j) {
    int g = j * 256 + tid;                        // 0..1023 : (row, chunk) slots
    int row = g >> 3, ch = g & 7;
    int mg = mtile * 128 + row;
    int bb = (unsigned)mg / NPIX; int rem = mg - bb * NPIX;
    int y = (unsigned)rem / HWDIM; int xx = rem - y * HWDIM;
    baseA[j] = ((bb * PPIX + y * PADW + xx) << 7) + ch * 8;   // padded-x element offset
    baseB[j] = (ntile * 128 + row) * KTOT + ch * 8;           // w^T element offset
    soff[j]  = row * 64 + ((ch ^ (row & 7)) << 3);            // XOR-swizzled LDS offset
  }
  f32x4 acc[4][4];
  #pragma unroll
  for (int mi = 0; mi < 4; ++mi)
    #pragma unroll
    for (int ni = 0; ni < 4; ++ni) acc[mi][ni] = (f32x4){0.f, 0.f, 0.f, 0.f};

  int ar = lane & 15, hi = lane >> 4, sx = lane & 7;

  u32x4 av[4], bv[4];
  #pragma unroll
  for (int j = 0; j < 4; ++j) {                   // prologue: tile t=0
    av[j] = *(const u32x4*)(xph + baseA[j]);
    bv[j] = *(const u32x4*)(wph + baseB[j]);
  }

  for (int t = 0; t < 18; ++t) {                  // K = 1152 = 9 taps * 2 c-halves of 64
    __syncthreads();
    #pragma unroll
    for (int j = 0; j < 4; ++j) {
      *(u32x4*)&As[soff[j]] = av[j];
      *(u32x4*)&Bs[soff[j]] = bv[j];
    }
    __syncthreads();
    if (t < 17) {                                 // next tile's loads retire under MFMAs
      int tn = t + 1;
      int kyx = tn >> 1;
      int ky = kyx / 3, kx = kyx - ky * 3;
      int koff = ((ky * PADW + kx) << 7) + ((tn & 1) << 6);
      #pragma unroll
      for (int j = 0; j < 4; ++j) {
        av[j] = *(const u32x4*)(xph + baseA[j] + koff);
        bv[j] = *(const u32x4*)(wph + baseB[j] + tn * 64);
      }
    }
    #pragma unroll
    for (int kk = 0; kk < 64; kk += 32) {
      int ch = (kk >> 3) + hi;
      int col = ((ch ^ sx) << 3);
      short8 af[4], bf8[4];
      #pragma unroll
      for (int mi = 0; mi < 4; ++mi) af[mi]  = *(const short8*)&As[(wr * 64 + mi * 16 + ar) * 64 + col];
      #pragma unroll
      for (int ni = 0; ni < 4; ++ni) bf8[ni] = *(const short8*)&Bs[(wc * 64 + ni * 16 + ar) * 64 + col];
      #pragma unroll
      for (int mi = 0; mi < 4; ++mi)
        #pragma unroll
        for (int ni = 0; ni < 4; ++ni)
          acc[mi][ni] = __builtin_amdgcn_mfma_f32_16x16x32_bf16(af[mi], bf8[ni], acc[mi][ni], 0, 0, 0);
    }
  }
  // epilogue: D col = lane&15 (o), row = (lane>>4)*4+j (m)  [m89-verified layout]
  int r4 = hi << 2;
  int cn = ar;
  #pragma unroll
  for (int ni = 0; ni < 4; ++ni) {
    int o = ntile * 128 + wc * 64 + ni * 16 + cn;
    float ms = mscale[o], bi = bias[o];
    #pragma unroll
    for (int mi = 0; mi < 4; ++mi) {
      int mg = mtile * 128 + wr * 64 + mi * 16 + r4;
      int bb = (unsigned)mg / NPIX; int pix = mg - bb * NPIX;
      f32x4 v;
      #pragma unroll
      for (int j = 0; j < 4; ++j) v[j] = (acc[mi][ni][j] + bi) * ms;
      *(f32x4*)(out + (size_t)(((b0 + bb) << 8) + o) * NPIX + pix) = v;
    }
  }
}

// ---------------- fallback value path (R3-verified): fp32 direct conv ----------------
__global__ __launch_bounds__(256) void k_dconv(const float* __restrict__ x,
    const float* __restrict__ w, const float* __restrict__ bias,
    const float* __restrict__ mscale, float* __restrict__ out) {
  int bid = blockIdx.x;
  int yq = bid % 14; int rem = bid / 14;
  int o = rem & 255; int b = rem >> 8;
  __shared__ float wsm[KTOT];
  for (int i = threadIdx.x; i < KTOT; i += 256) wsm[i] = w[o * KTOT + i];
  __syncthreads();
  int t = threadIdx.x;
  if (t >= 224) return;
  int y = yq * 4 + t / HWDIM;
  int xx = t % HWDIM;
  const float* xb = x + (size_t)b * C_IN * NPIX + y * HWDIM + xx;
  float acc = 0.f;
  bool y0 = y > 0, y2 = y < HWDIM - 1, x0 = xx > 0, x2 = xx < HWDIM - 1;
  for (int c = 0; c < C_IN; ++c) {
    const float* xc = xb + c * NPIX;
    const float* wc9 = wsm + c * 9;
    float s = xc[0] * wc9[4];
    if (x0) s += xc[-1] * wc9[3];
    if (x2) s += xc[1] * wc9[5];
    if (y0) { s += xc[-HWDIM] * wc9[1]; if (x0) s += xc[-HWDIM - 1] * wc9[0]; if (x2) s += xc[-HWDIM + 1] * wc9[2]; }
    if (y2) { s += xc[HWDIM] * wc9[7];  if (x0) s += xc[HWDIM - 1] * wc9[6];  if (x2) s += xc[HWDIM + 1] * wc9[8]; }
    acc += s;
  }
  out[((size_t)b * O_CH + o) * NPIX + y * HWDIM + xx] = (acc + bias[o]) * mscale[o];
}

extern "C" void kernel_launch(void* const* d_in, const int* in_sizes, int n_in,
                              void* d_out, int out_size, void* d_ws, size_t ws_size,
                              hipStream_t stream) {
  const float* x      = (const float*)d_in[0];
  const float* w      = (const float*)d_in[1];
  const float* bias   = (const float*)d_in[2];
  const float* a      = (const float*)d_in[3];
  const float* b_unit = (const float*)d_in[4];
  float* out = (float*)d_out;
  char* ws = (char*)d_ws;

  // small fixed region (bytes)
  int*    ghist   = (int*)   (ws);                // NHC*5*2048*4 = 327,680
  double* ssbuf   = (double*)(ws + 327680);       //  2,048 -> 329,728
  int*    kbucket = (int*)   (ws + 329728);       //  5,120 -> 334,848
  float*  mscale  = (float*) (ws + 334848);       //  1,024 -> 335,872
  float*  apk     = (float*) (ws + 335872);       // 24,576 -> 360,448
  const size_t SMALL = 360448;
  const size_t PDOT  = 8028160;                   // 4*5*100352*4
  float* pdot = (float*)(ws + SMALL);

  hipMemsetAsync(ghist, 0, NHC * NH * TSIZE * 4, stream);
  k_norms <<<256, 64, 0, stream>>>(w, ssbuf);
  k_table <<<256, 256, 0, stream>>>(w, a, b_unit, ssbuf, kbucket);

  bool twopass = ws_size >= SMALL + PDOT;
  if (twopass) {
    k_packa <<<23, 256, 0, stream>>>(a, apk);
    k_vote3a<<<dim3(392, 4), 256, 0, stream>>>(x, apk, pdot);
    k_vote3b<<<392, 256, 0, stream>>>(pdot, a, b_unit, ghist);
  } else {
    k_vote2 <<<1568, 256, 0, stream>>>(x, a, b_unit, ghist);
  }
  k_select<<<1, 256, 0, stream>>>(ghist, kbucket, mscale);

  // ws-adaptive batch slicing for the bf16 GEMM path
  const size_t GBASE = SMALL + (twopass ? PDOT : 0);
  const size_t WPT = 589824;                      // 256*1152*2
  const size_t XPB = 861184;                      // 3364*128*2 per batch
  int NB = 0;
  for (int nb = 32; nb >= 2; nb -= 2)
    if (GBASE + WPT + (size_t)nb * XPB <= ws_size) { NB = nb; break; }

  if (NB == 0) {                                  // ws too small: verified fallback
    k_dconv<<<32 * 256 * 14, 256, 0, stream>>>(x, w, bias, mscale, out);
    return;
  }

  unsigned short* wph = (unsigned short*)(ws + GBASE);
  unsigned short* xph = (unsigned short*)(ws + GBASE + WPT);

  k_packw1<<<1152, 256, 0, stream>>>(w, wph);
  k_ring  <<<NB * PADW, 256, 0, stream>>>(xph);   // zero pad ring only (interiors overwritten)

  for (int b0 = 0; b0 < 32; b0 += NB) {
    int nb = NB < (32 - b0) ? NB : (32 - b0);     // even (NB even, 32 even)
    k_packx1<<<nb * HWDIM, 256, 0, stream>>>(x, b0, xph);
    int mtiles = nb * NPIX / 128;                 // nb even -> exact
    k_gemm1<<<mtiles * 2, 256, 0, stream>>>(xph, wph, bias, mscale, out, b0);
  }
}

// Round 9
// 217.826 us; speedup vs baseline: 9.2338x; 1.0617x over previous
//
#include <hip/hip_runtime.h>
#include <hip/hip_bf16.h>
#include <stdint.h>

typedef __attribute__((ext_vector_type(8))) short  short8;   // 8 x bf16 fragment
typedef __attribute__((ext_vector_type(4))) float  f32x4;
typedef __attribute__((ext_vector_type(4))) unsigned int u32x4;

#define C_IN  128
#define O_CH  256
#define NH    5
#define TSIZE 2048
#define HWDIM 56
#define NPIX  3136        // 56*56
#define MTOT  100352      // 32*3136
#define KTOT  1152        // 128*9
#define ADIM  1161        // KTOT + 9
#define PADW  58
#define PPIX  3364        // 58*58
#define NHC   8           // global-hist copies
#define LBINS 192         // LDS hist bins per hash (spill path covers the rest)

static __device__ __forceinline__ unsigned short f2bf(float f) {
  unsigned int u = __float_as_uint(f);
  return (unsigned short)((u + 0x7fffu + ((u >> 16) & 1u)) >> 16);   // RNE
}

// ---------------- table build (fp64 decision path — verified R3..R8) ----------------
__global__ void k_norms(const float* __restrict__ w, double* __restrict__ ssbuf) {
  int o = blockIdx.x, t = threadIdx.x;            // 64 threads
  double ss = 0.;
  for (int i = t; i < KTOT; i += 64) { double v = (double)w[o * KTOT + i]; ss += v * v; }
  #pragma unroll
  for (int off = 32; off > 0; off >>= 1) ss += __shfl_down(ss, off, 64);
  if (t == 0) ssbuf[o] = ss;
}

__global__ __launch_bounds__(256) void k_table(const float* __restrict__ w,
    const float* __restrict__ a, const float* __restrict__ b_unit,
    const double* __restrict__ ssbuf, int* __restrict__ kbucket) {
  int o = blockIdx.x, t = threadIdx.x;
  __shared__ double red[256];
  __shared__ double r6[6][256];
  red[t] = ssbuf[t];
  __syncthreads();
  for (int s = 128; s; s >>= 1) { if (t < s) red[t] = fmax(red[t], red[t + s]); __syncthreads(); }
  double scale = 0.99 / sqrt(red[0]);             // U / denom
  double pd0 = 0, pd1 = 0, pd2 = 0, pd3 = 0, pd4 = 0, ss2 = 0;
  for (int i = t; i < KTOT; i += 256) {
    double wv = scale * (double)w[o * KTOT + i];
    ss2 += wv * wv;
    pd0 += wv * (double)a[0 * ADIM + i];
    pd1 += wv * (double)a[1 * ADIM + i];
    pd2 += wv * (double)a[2 * ADIM + i];
    pd3 += wv * (double)a[3 * ADIM + i];
    pd4 += wv * (double)a[4 * ADIM + i];
  }
  r6[0][t] = ss2; r6[1][t] = pd0; r6[2][t] = pd1; r6[3][t] = pd2; r6[4][t] = pd3; r6[5][t] = pd4;
  __syncthreads();
  for (int s = 128; s; s >>= 1) {
    if (t < s) { for (int q = 0; q < 6; ++q) r6[q][t] += r6[q][t + s]; }
    __syncthreads();
  }
  if (t == 0) {
    double nrm = sqrt(r6[0][0]);
    double q = nrm;
    double dp[NH] = {0, 0, 0, 0, 0};
    for (int j = 0; j < 9; ++j) {
      q = q * q;                                   // nrm^2, nrm^4, ..., nrm^512
      #pragma unroll
      for (int h = 0; h < NH; ++h) dp[h] += q * (double)a[h * ADIM + KTOT + j];
    }
    #pragma unroll
    for (int h = 0; h < NH; ++h) {
      double tot = r6[1 + h][0] + dp[h] + (double)b_unit[h] * 4.0;
      int hv = (int)floor(tot * 0.25);
      int bk = hv % TSIZE; if (bk < 0) bk = -bk;
      kbucket[o * NH + h] = bk;
    }
  }
}

// ---------------- a repack: apk[c][48] = a[h*ADIM + c*9 + k] at [c*48 + h*9 + k] ----------------
__global__ void k_packa(const float* __restrict__ a, float* __restrict__ apk) {
  int i = blockIdx.x * 256 + threadIdx.x;         // 128*45 = 5760
  if (i >= C_IN * 45) return;
  int c = i / 45, r = i - c * 45;                 // r = h*9+k
  int h = r / 9, k = r - h * 9;
  apk[c * 48 + r] = a[h * ADIM + c * 9 + k];
}

// ---------------- vote pass 1: 2 adjacent px/thread, shared 3x4 tap window ----------------
__global__ __launch_bounds__(256) void k_vote3a(const float* __restrict__ x,
    const float* __restrict__ apk, float* __restrict__ pdot) {
  int g = blockIdx.y;                             // channel group 0..3 (block-uniform)
  int t = threadIdx.x;
  int p0 = blockIdx.x * 512 + t * 2;              // 196*512 = 100352 exact; p0 even
  int bb = p0 / NPIX; int rem = p0 - bb * NPIX;
  int y = rem / HWDIM; int xxL = rem - y * HWDIM; // even, 0..54; both px same row
  bool xm = xxL > 0, xp = xxL < HWDIM - 2;        // col-1 valid / col+2 valid
  bool y0 = y > 0, y2 = y < HWDIM - 1;
  const float* xb = x + ((size_t)bb * C_IN + g * 32) * NPIX + y * HWDIM + xxL;
  const float* ap = apk + (g * 32) * 48;          // uniform base -> scalar loads
  float aL[NH] = {0, 0, 0, 0, 0}, aR[NH] = {0, 0, 0, 0, 0};
  for (int c = 0; c < 32; ++c) {
    const float* xc = xb + c * NPIX;
    float t0m = 0, t00 = 0, t01 = 0, t02 = 0;
    float m0m = 0, m02 = 0;
    float b0m = 0, b00 = 0, b01 = 0, b02 = 0;
    float m00 = xc[0], m01 = xc[1];
    if (xm) m0m = xc[-1];
    if (xp) m02 = xc[2];
    if (y0) { t00 = xc[-HWDIM]; t01 = xc[-HWDIM + 1]; if (xm) t0m = xc[-HWDIM - 1]; if (xp) t02 = xc[-HWDIM + 2]; }
    if (y2) { b00 = xc[HWDIM];  b01 = xc[HWDIM + 1];  if (xm) b0m = xc[HWDIM - 1];  if (xp) b02 = xc[HWDIM + 2]; }
    const float* ac = ap + c * 48;
    #pragma unroll
    for (int h = 0; h < NH; ++h) {
      const float* ah = ac + h * 9;
      aL[h] += t0m * ah[0] + t00 * ah[1] + t01 * ah[2] + m0m * ah[3] + m00 * ah[4]
             + m01 * ah[5] + b0m * ah[6] + b00 * ah[7] + b01 * ah[8];
      aR[h] += t00 * ah[0] + t01 * ah[1] + t02 * ah[2] + m00 * ah[3] + m01 * ah[4]
             + m02 * ah[5] + b00 * ah[6] + b01 * ah[7] + b02 * ah[8];
    }
  }
  #pragma unroll
  for (int h = 0; h < NH; ++h) {
    float2 v = make_float2(aL[h], aR[h]);
    *(float2*)&pdot[((size_t)g * NH + h) * MTOT + p0] = v;
  }
}

// ---------------- vote pass 2: deterministic group-sum + bin (R5 expression order) ----------------
__global__ __launch_bounds__(256) void k_vote3b(const float* __restrict__ pdot,
    const float* __restrict__ a, const float* __restrict__ b_unit, int* __restrict__ ghist) {
  __shared__ int lh[NH * LBINS];
  int t = threadIdx.x;
  for (int i = t; i < NH * LBINS; i += 256) lh[i] = 0;
  __syncthreads();
  int p = blockIdx.x * 256 + t;                   // 392*256 = 100352 exact
  int bb = p / NPIX; int rem = p - bb * NPIX;
  int y = rem / HWDIM; int xx = rem - y * HWDIM;
  bool x0 = xx > 0, x2 = xx < HWDIM - 1, y0 = y > 0, y2 = y < HWDIM - 1;
  int* gh = ghist + (blockIdx.x & (NHC - 1)) * NH * TSIZE;
  #pragma unroll
  for (int h = 0; h < NH; ++h) {
    float s = pdot[((size_t)0 * NH + h) * MTOT + p] + pdot[((size_t)1 * NH + h) * MTOT + p]
            + pdot[((size_t)2 * NH + h) * MTOT + p] + pdot[((size_t)3 * NH + h) * MTOT + p];
    const float* ah = a + h * ADIM + KTOT;        // appended 0.5 channel (zero pad ring)
    float e = ah[4];
    if (x0) e += ah[3];
    if (x2) e += ah[5];
    if (y0) { e += ah[1]; if (x0) e += ah[0]; if (x2) e += ah[2]; }
    if (y2) { e += ah[7]; if (x0) e += ah[6]; if (x2) e += ah[8]; }
    s += 0.5f * e;
    int hv = (int)floorf((s + b_unit[h] * 4.0f) * 0.25f);
    int bk = hv % TSIZE; if (bk < 0) bk = -bk;
    if (bk < LBINS) atomicAdd(&lh[h * LBINS + bk], 1);
    else            atomicAdd(&gh[h * TSIZE + bk], 1);     // rare spill
  }
  __syncthreads();
  for (int i = t; i < NH * LBINS; i += 256) {
    int v = lh[i];
    if (v) { int h = i / LBINS, bk = i - h * LBINS; atomicAdd(&gh[h * TSIZE + bk], v); }
  }
}

// ---------------- vote fallback (verified R5): single-pass, used only if ws is tiny ----------------
__global__ __launch_bounds__(256) void k_vote2(const float* __restrict__ x,
    const float* __restrict__ a, const float* __restrict__ b_unit, int* __restrict__ ghist) {
  __shared__ float red[4][NH][64];
  __shared__ int   lh[NH * LBINS];
  int t = threadIdx.x;
  int px = t & 63, g = t >> 6;
  for (int i = t; i < NH * LBINS; i += 256) lh[i] = 0;
  int p = blockIdx.x * 64 + px;
  int bb = p / NPIX; int rem = p - bb * NPIX;
  int y = rem / HWDIM; int xx = rem - y * HWDIM;
  bool x0 = xx > 0, x2 = xx < HWDIM - 1, y0 = y > 0, y2 = y < HWDIM - 1;
  const float* xb = x + ((size_t)bb * C_IN + g * 32) * NPIX + y * HWDIM + xx;
  float acc[NH] = {0, 0, 0, 0, 0};
  for (int c = 0; c < 32; ++c) {
    const float* xc = xb + c * NPIX;
    float v0 = 0, v1 = 0, v2 = 0, v3 = 0, v5 = 0, v6 = 0, v7 = 0, v8 = 0;
    float v4 = xc[0];
    if (x0) v3 = xc[-1];
    if (x2) v5 = xc[1];
    if (y0) { v1 = xc[-HWDIM]; if (x0) v0 = xc[-HWDIM - 1]; if (x2) v2 = xc[-HWDIM + 1]; }
    if (y2) { v7 = xc[HWDIM];  if (x0) v6 = xc[HWDIM - 1];  if (x2) v8 = xc[HWDIM + 1]; }
    #pragma unroll
    for (int h = 0; h < NH; ++h) {
      const float* ah = a + h * ADIM + (g * 32 + c) * 9;
      acc[h] += v0 * ah[0] + v1 * ah[1] + v2 * ah[2] + v3 * ah[3] + v4 * ah[4]
              + v5 * ah[5] + v6 * ah[6] + v7 * ah[7] + v8 * ah[8];
    }
  }
  #pragma unroll
  for (int h = 0; h < NH; ++h) red[g][h][px] = acc[h];
  __syncthreads();
  int* gh = ghist + (blockIdx.x & (NHC - 1)) * NH * TSIZE;
  if (g == 0) {
    #pragma unroll
    for (int h = 0; h < NH; ++h) {
      float s = red[0][h][px] + red[1][h][px] + red[2][h][px] + red[3][h][px];
      const float* ah = a + h * ADIM + KTOT;
      float e = ah[4];
      if (x0) e += ah[3];
      if (x2) e += ah[5];
      if (y0) { e += ah[1]; if (x0) e += ah[0]; if (x2) e += ah[2]; }
      if (y2) { e += ah[7]; if (x0) e += ah[6]; if (x2) e += ah[8]; }
      s += 0.5f * e;
      int hv = (int)floorf((s + b_unit[h] * 4.0f) * 0.25f);
      int bk = hv % TSIZE; if (bk < 0) bk = -bk;
      if (bk < LBINS) atomicAdd(&lh[h * LBINS + bk], 1);
      else            atomicAdd(&gh[h * TSIZE + bk], 1);
    }
  }
  __syncthreads();
  for (int i = t; i < NH * LBINS; i += 256) {
    int v = lh[i];
    if (v) { int h = i / LBINS, bk = i - h * LBINS; atomicAdd(&gh[h * TSIZE + bk], v); }
  }
}

// ---------------- argmax per hash (5 blocks) + mask (1 block) — semantics == R5 k_select ----------------
__global__ __launch_bounds__(256) void k_argmax(const int* __restrict__ ghist, int* __restrict__ sel) {
  int h = blockIdx.x;                             // 0..4
  int t = threadIdx.x;
  __shared__ int rc[256], ri[256];
  int bc = -1, bi = 0;
  for (int i = t; i < TSIZE; i += 256) {          // ascending i + strict '>' = first-max
    int c = 0;
    #pragma unroll
    for (int k = 0; k < NHC; ++k) c += ghist[(k * NH + h) * TSIZE + i];
    if (c > bc) { bc = c; bi = i; }
  }
  rc[t] = bc; ri[t] = bi;
  __syncthreads();
  for (int s = 128; s; s >>= 1) {
    if (t < s) {
      if (rc[t + s] > rc[t] || (rc[t + s] == rc[t] && ri[t + s] < ri[t])) {
        rc[t] = rc[t + s]; ri[t] = ri[t + s];
      }
    }
    __syncthreads();
  }
  if (t == 0) sel[h] = ri[0];
}

__global__ __launch_bounds__(256) void k_mask(const int* __restrict__ sel,
    const int* __restrict__ kbucket, float* __restrict__ mscale) {
  int t = threadIdx.x;
  __shared__ int cnt[256], ssel[NH];
  if (t < NH) ssel[t] = sel[t];
  __syncthreads();
  bool act = false;
  #pragma unroll
  for (int i = 0; i < NH; ++i) {
    int kb = kbucket[t * NH + i];
    #pragma unroll
    for (int j = 0; j < NH; ++j) act = act || (kb == ssel[j]);
  }
  cnt[t] = act ? 1 : 0;
  __syncthreads();
  for (int s = 128; s; s >>= 1) { if (t < s) cnt[t] += cnt[t + s]; __syncthreads(); }
  int n = cnt[0];
  bool a2 = act;
  if (n == 0) { a2 = true; n = 256; }             // fallback: all active
  mscale[t] = a2 ? 256.0f / (float)n : 0.0f;
}

// ---------------- packing: plain bf16 ----------------
__global__ void k_packw1(const float* __restrict__ w, unsigned short* __restrict__ wph) {
  int idx = blockIdx.x * 256 + threadIdx.x;       // < 294912 exact
  int o = idx / KTOT; int r = idx - o * KTOT;
  int kyx = r >> 7; int c = r & 127;
  wph[idx] = f2bf(w[o * KTOT + c * 9 + kyx]);
}

__global__ __launch_bounds__(256) void k_packx1(const float* __restrict__ x, int b0,
                                                unsigned short* __restrict__ xph) {
  int bl = blockIdx.x / HWDIM; int y = blockIdx.x - bl * HWDIM;   // bl = slice-local batch
  int t = threadIdx.x;
  __shared__ unsigned short th[C_IN * 57];        // +1 pad on 56
  const float* xb = x + (size_t)((b0 + bl) * C_IN) * NPIX + y * HWDIM;
  for (int i = t; i < C_IN * HWDIM; i += 256) {
    int c = i / HWDIM; int xx = i - c * HWDIM;
    th[c * 57 + xx] = f2bf(xb[c * NPIX + xx]);
  }
  __syncthreads();
  size_t base = ((size_t)(bl * PADW + y + 1) * PADW + 1) * C_IN;
  for (int i = t; i < C_IN * HWDIM; i += 256) {
    int xx = i >> 7; int c = i & 127;
    xph[base + xx * C_IN + c] = th[c * 57 + xx];
  }
}

// ---------------- pad-ring zeroing ----------------
__global__ __launch_bounds__(256) void k_ring(unsigned short* __restrict__ xph) {
  int r = blockIdx.x % PADW;                      // plane row 0..57
  int bl = blockIdx.x / PADW;                     // slab
  unsigned short* row = xph + ((size_t)bl * PPIX + (size_t)r * PADW) * C_IN;
  int t = threadIdx.x;
  if (r == 0 || r == PADW - 1) {
    for (int i = t; i < PADW * C_IN; i += 256) row[i] = 0;
  } else {
    if (t < 128) row[t] = 0;                      // col 0
    else row[57 * C_IN + (t - 128)] = 0;          // col 57
  }
}

// ---------------- main conv: bf16 MFMA GEMM, swizzled LDS, double-buffer 1-barrier ----------------
__global__ __launch_bounds__(256) void k_gemm1(
    const unsigned short* __restrict__ xph, const unsigned short* __restrict__ wph,
    const float* __restrict__ bias, const float* __restrict__ mscale,
    float* __restrict__ out, int b0) {
  int mtile = blockIdx.x >> 1;                    // M-tiles of 128 pixels (slice-local)
  int ntile = blockIdx.x & 1;                     // 2 N-tiles of 128 out-channels
  int tid = threadIdx.x;
  int lane = tid & 63, wv = tid >> 6;
  int wr = wv >> 1, wc = wv & 1;                  // 2x2 wave grid, 64x64 each
  __shared__ __attribute__((aligned(16))) unsigned short As[2][128 * 64];   // 2 x 16 KB
  __shared__ __attribute__((aligned(16))) unsigned short Bs[2][128 * 64];   // 2 x 16 KB
  int baseA[4], baseB[4], soff[4];
  #pragma unroll
  for (int j = 0; j < 4; ++j) {
    int g = j * 256 + tid;                        // 0..1023 : (row, chunk) slots
    int row = g >> 3, ch = g & 7;
    int mg = mtile * 128 + row;
    int bb = (unsigned)mg / NPIX; int rem = mg - bb * NPIX;
    int y = (unsigned)rem / HWDIM; int xx = rem - y * HWDIM;
    baseA[j] = ((bb * PPIX + y * PADW + xx) << 7) + ch * 8;   // padded-x element offset
    baseB[j] = (ntile * 128 + row) * KTOT + ch * 8;           // w^T element offset
    soff[j]  = row * 64 + ((ch ^ (row & 7)) << 3);            // XOR-swizzled LDS offset
  }
  f32x4 acc[4][4];
  #pragma unroll
  for (int mi = 0; mi < 4; ++mi)
    #pragma unroll
    for (int ni = 0; ni < 4; ++ni) acc[mi][ni] = (f32x4){0.f, 0.f, 0.f, 0.f};

  int ar = lane & 15, hi = lane >> 4, sx = lane & 7;

  u32x4 av[4], bv[4];
  #pragma unroll
  for (int j = 0; j < 4; ++j) {                   // prologue: load tile 0 and stage into buf 0
    av[j] = *(const u32x4*)(xph + baseA[j]);
    bv[j] = *(const u32x4*)(wph + baseB[j]);
  }
  #pragma unroll
  for (int j = 0; j < 4; ++j) {
    *(u32x4*)&As[0][soff[j]] = av[j];
    *(u32x4*)&Bs[0][soff[j]] = bv[j];
  }

  for (int t = 0; t < 18; ++t) {                  // K = 1152 = 9 taps * 2 c-halves of 64
    int cur = t & 1;
    __syncthreads();                              // buf[cur] writes visible; prev readers done
    if (t < 17) {                                 // issue next tile's loads (retire under MFMAs)
      int tn = t + 1;
      int kyx = tn >> 1;
      int ky = kyx / 3, kx = kyx - ky * 3;
      int koff = ((ky * PADW + kx) << 7) + ((tn & 1) << 6);
      #pragma unroll
      for (int j = 0; j < 4; ++j) {
        av[j] = *(const u32x4*)(xph + baseA[j] + koff);
        bv[j] = *(const u32x4*)(wph + baseB[j] + tn * 64);
      }
    }
    #pragma unroll
    for (int kk = 0; kk < 64; kk += 32) {
      int ch = (kk >> 3) + hi;
      int col = ((ch ^ sx) << 3);
      short8 af[4], bf8[4];
      #pragma unroll
      for (int mi = 0; mi < 4; ++mi) af[mi]  = *(const short8*)&As[cur][(wr * 64 + mi * 16 + ar) * 64 + col];
      #pragma unroll
      for (int ni = 0; ni < 4; ++ni) bf8[ni] = *(const short8*)&Bs[cur][(wc * 64 + ni * 16 + ar) * 64 + col];
      #pragma unroll
      for (int mi = 0; mi < 4; ++mi)
        #pragma unroll
        for (int ni = 0; ni < 4; ++ni)
          acc[mi][ni] = __builtin_amdgcn_mfma_f32_16x16x32_bf16(af[mi], bf8[ni], acc[mi][ni], 0, 0, 0);
    }
    if (t < 17) {                                 // stage t+1 into the other buffer (no WAR: see barrier walk)
      #pragma unroll
      for (int j = 0; j < 4; ++j) {
        *(u32x4*)&As[cur ^ 1][soff[j]] = av[j];
        *(u32x4*)&Bs[cur ^ 1][soff[j]] = bv[j];
      }
    }
  }
  // epilogue: D col = lane&15 (o), row = (lane>>4)*4+j (m)  [m89-verified layout]
  int r4 = hi << 2;
  int cn = ar;
  #pragma unroll
  for (int ni = 0; ni < 4; ++ni) {
    int o = ntile * 128 + wc * 64 + ni * 16 + cn;
    float ms = mscale[o], bi = bias[o];
    #pragma unroll
    for (int mi = 0; mi < 4; ++mi) {
      int mg = mtile * 128 + wr * 64 + mi * 16 + r4;
      int bb = (unsigned)mg / NPIX; int pix = mg - bb * NPIX;
      f32x4 v;
      #pragma unroll
      for (int j = 0; j < 4; ++j) v[j] = (acc[mi][ni][j] + bi) * ms;
      *(f32x4*)(out + (size_t)(((b0 + bb) << 8) + o) * NPIX + pix) = v;
    }
  }
}

// ---------------- fallback value path (R3-verified): fp32 direct conv ----------------
__global__ __launch_bounds__(256) void k_dconv(const float* __restrict__ x,
    const float* __restrict__ w, const float* __restrict__ bias,
    const float* __restrict__ mscale, float* __restrict__ out) {
  int bid = blockIdx.x;
  int yq = bid % 14; int rem = bid / 14;
  int o = rem & 255; int b = rem >> 8;
  __shared__ float wsm[KTOT];
  for (int i = threadIdx.x; i < KTOT; i += 256) wsm[i] = w[o * KTOT + i];
  __syncthreads();
  int t = threadIdx.x;
  if (t >= 224) return;
  int y = yq * 4 + t / HWDIM;
  int xx = t % HWDIM;
  const float* xb = x + (size_t)b * C_IN * NPIX + y * HWDIM + xx;
  float acc = 0.f;
  bool y0 = y > 0, y2 = y < HWDIM - 1, x0 = xx > 0, x2 = xx < HWDIM - 1;
  for (int c = 0; c < C_IN; ++c) {
    const float* xc = xb + c * NPIX;
    const float* wc9 = wsm + c * 9;
    float s = xc[0] * wc9[4];
    if (x0) s += xc[-1] * wc9[3];
    if (x2) s += xc[1] * wc9[5];
    if (y0) { s += xc[-HWDIM] * wc9[1]; if (x0) s += xc[-HWDIM - 1] * wc9[0]; if (x2) s += xc[-HWDIM + 1] * wc9[2]; }
    if (y2) { s += xc[HWDIM] * wc9[7];  if (x0) s += xc[HWDIM - 1] * wc9[6];  if (x2) s += xc[HWDIM + 1] * wc9[8]; }
    acc += s;
  }
  out[((size_t)b * O_CH + o) * NPIX + y * HWDIM + xx] = (acc + bias[o]) * mscale[o];
}

extern "C" void kernel_launch(void* const* d_in, const int* in_sizes, int n_in,
                              void* d_out, int out_size, void* d_ws, size_t ws_size,
                              hipStream_t stream) {
  const float* x      = (const float*)d_in[0];
  const float* w      = (const float*)d_in[1];
  const float* bias   = (const float*)d_in[2];
  const float* a      = (const float*)d_in[3];
  const float* b_unit = (const float*)d_in[4];
  float* out = (float*)d_out;
  char* ws = (char*)d_ws;

  // small fixed region (bytes)
  int*    ghist   = (int*)   (ws);                // NHC*5*2048*4 = 327,680
  double* ssbuf   = (double*)(ws + 327680);       //  2,048 -> 329,728
  int*    kbucket = (int*)   (ws + 329728);       //  5,120 -> 334,848
  float*  mscale  = (float*) (ws + 334848);       //  1,024 -> 335,872
  float*  apk     = (float*) (ws + 335872);       // 24,576 -> 360,448
  int*    sel     = (int*)   (ws + 360448);       //     64 -> 360,512
  const size_t SMALL = 360512;
  const size_t PDOT  = 8028160;                   // 4*5*100352*4
  float* pdot = (float*)(ws + SMALL);

  hipMemsetAsync(ghist, 0, NHC * NH * TSIZE * 4, stream);
  k_norms <<<256, 64, 0, stream>>>(w, ssbuf);
  k_table <<<256, 256, 0, stream>>>(w, a, b_unit, ssbuf, kbucket);

  bool twopass = ws_size >= SMALL + PDOT;
  if (twopass) {
    k_packa <<<23, 256, 0, stream>>>(a, apk);
    k_vote3a<<<dim3(196, 4), 256, 0, stream>>>(x, apk, pdot);
    k_vote3b<<<392, 256, 0, stream>>>(pdot, a, b_unit, ghist);
  } else {
    k_vote2 <<<1568, 256, 0, stream>>>(x, a, b_unit, ghist);
  }
  k_argmax<<<NH, 256, 0, stream>>>(ghist, sel);
  k_mask  <<<1, 256, 0, stream>>>(sel, kbucket, mscale);

  // ws-adaptive batch slicing for the bf16 GEMM path
  const size_t GBASE = SMALL + (twopass ? PDOT : 0);
  const size_t WPT = 589824;                      // 256*1152*2
  const size_t XPB = 861184;                      // 3364*128*2 per batch
  int NB = 0;
  for (int nb = 32; nb >= 2; nb -= 2)
    if (GBASE + WPT + (size_t)nb * XPB <= ws_size) { NB = nb; break; }

  if (NB == 0) {                                  // ws too small: verified fallback
    k_dconv<<<32 * 256 * 14, 256, 0, stream>>>(x, w, bias, mscale, out);
    return;
  }

  unsigned short* wph = (unsigned short*)(ws + GBASE);
  unsigned short* xph = (unsigned short*)(ws + GBASE + WPT);

  k_packw1<<<1152, 256, 0, stream>>>(w, wph);
  k_ring  <<<NB * PADW, 256, 0, stream>>>(xph);   // zero pad ring only (interiors overwritten)

  for (int b0 = 0; b0 < 32; b0 += NB) {
    int nb = NB < (32 - b0) ? NB : (32 - b0);     // even (NB even, 32 even)
    k_packx1<<<nb * HWDIM, 256, 0, stream>>>(x, b0, xph);
    int mtiles = nb * NPIX / 128;                 // nb even -> exact
    k_gemm1<<<mtiles * 2, 256, 0, stream>>>(xph, wph, bias, mscale, out, b0);
  }
}